// Round 13
// baseline (276.893 us; speedup 1.0000x reference)
//
#include <hip/hip_runtime.h>
#include <math.h>

#define EPSV 1e-10f

typedef _Float16 f16x8 __attribute__((ext_vector_type(8)));
typedef _Float16 f16x4 __attribute__((ext_vector_type(4)));
typedef float f32x4 __attribute__((ext_vector_type(4)));

// ---------------- agg LDS layout (bytes), R19 (32KB) ----------------
// A (0..8192):      W1T f16 [64][128] swz (P2a-B4) -> 4 wave-private H slots
//                   (wave*2048, 16 rows x 128B) in main loop; csW at flush.
// B (8192..16384):  W2T[n2][h] f16 swz (P2a -> end)
// C (16384..24576): M2T[n3][h] f16 swz (P2b -> end)
// D (24576..28672): cstP f32 4x64 (24576..25600) + sR1 f32 [6][68]
//                   (25856.., = R1 + b1 folded, live in main loop)
// E (28672..32768): sV[g][n], g < 16  (written by OWNING wave in P1)
// R19: AU and uS are GONE (P1 is register-resident with coalesced global
// reads) -> no overlays, prologue barriers reduced 5 -> 2.
#define OFF_W1T  0
#define OFF_W2T  8192
#define OFF_M2T  16384
#define OFF_U    24576
#define OFF_R1   25856
#define OFF_V    28672
#define SMEM_SZ  32768

__device__ __forceinline__ f16x8 cvt_f16x8(const float4 a, const float4 b) {
  f16x8 h;
  h[0] = (_Float16)a.x; h[1] = (_Float16)a.y; h[2] = (_Float16)a.z; h[3] = (_Float16)a.w;
  h[4] = (_Float16)b.x; h[5] = (_Float16)b.y; h[6] = (_Float16)b.z; h[7] = (_Float16)b.w;
  return h;
}

// DPP quad_perm adds: exact xor-1 / xor-2 cross-lane sums at VALU speed.
__device__ __forceinline__ float qpx1_add(float x) {
  return x + __int_as_float(__builtin_amdgcn_update_dpp(
                 0, __float_as_int(x), 0xB1, 0xF, 0xF, false));
}
__device__ __forceinline__ float qpx2_add(float x) {
  return x + __int_as_float(__builtin_amdgcn_update_dpp(
                 0, __float_as_int(x), 0x4E, 0xF, 0xF, false));
}

// ---------------------------------------------------------------------------
// Fused item-aggregation. I-blocks FIRST [0,nIblk): 4 groups (P=100, 1/wave);
// S-blocks after: 16 groups (P=40, 4/wave). 256 thr = 4 waves.
// R19: PROLOGUE attack. Occupancy-derived wave lifetime ~49us over 12 tiles
// + R11's marginal prologue cost (~13-29us/block) => prologue is 30-60% of
// block time; all main-loop optimizations (R9/R17/R18) were null because
// they attacked the minority term.
// (a) AU + uS deleted: P1 computes v[g][j] in REGISTERS via column-coalesced
//     L2-hot atti_W1 reads + wave-uniform user reads; wave w owns groups
//     g=w mod 4 -> sV self-produced, NO barrier. Removes 128 b128 LDS
//     reads/thread + AU scatter staging + 2 barriers.
// (b) aW hoist moved before P2b -> merges B4/B5. Barriers 5 -> 2.
// (c) gather prefetch issued at kernel TOP (cold-HBM latency hides under
//     the whole prologue).
// Main loop = R18 verbatim (ballot mask + DPP reduce, proven).
// Tripwires: FETCH ~101MB / WRITE ~5.2MB / VGPR 80-95 / conflicts ~4M.
// ---------------------------------------------------------------------------
__global__ __launch_bounds__(256, 3) void agg_kernel(
    const int nIblk,
    const int* __restrict__ idsS, const int* __restrict__ uidS,
    const int* __restrict__ idsI, const int* __restrict__ uidI,
    const float* __restrict__ user_table, const float* __restrict__ item_table,
    const float* __restrict__ rate_table,
    const float* __restrict__ gv_W1, const float* __restrict__ gv_b1,
    const float* __restrict__ gv_W2, const float* __restrict__ gv_b2,
    const float* __restrict__ atti_W1, const float* __restrict__ atti_b1,
    const float* __restrict__ atti_W2, const float* __restrict__ atti_b2,
    const float* __restrict__ agg_W, const float* __restrict__ agg_b,
    float* __restrict__ outS, float* __restrict__ outI) {
  __shared__ __align__(16) char smem[SMEM_SZ];
  const int tid = threadIdx.x;
  const int wave = tid >> 6, lane = tid & 63;
  const int quad = lane >> 4, mrow = lane & 15;

  const bool isS = (int)blockIdx.x >= nIblk;
  const int P = isS ? 40 : 100;
  const int nGrp = isS ? 4 : 1;  // groups per wave
  const int tpg = isS ? 3 : 8;   // 16-row tiles per group
  const int nIdx = nGrp * tpg;   // 12 or 8
  const int* __restrict__ ids = isS ? idsS : idsI;
  const int* __restrict__ uidp = isS ? uidS : uidI;
  float* __restrict__ out = isS ? outS : outI;
  const int gbase = isS ? ((int)blockIdx.x - nIblk) * 16 : (int)blockIdx.x * 4;

  float* sV = (float*)(smem + OFF_V);
  char* smXw = smem + OFF_W1T + wave * 2048;  // wave-private H slot (post-B4)
  float* csW = (float*)smXw;                  // epilogue c vector (H dead then)

  // ---- gather prefetch pipeline (issued FIRST: cold latency hides under
  //      the whole prologue) ----
  const int nIdxM1 = nIdx - 1;
  int2 idreg;
  float4 pf[4];
  float pm;
  int rid;
  auto load_ids = [&](int idx) __attribute__((always_inline)) {
    const int ic = idx < nIdxM1 ? idx : nIdxM1;  // clamp (tail prefetch harmless)
    const int gq = isS ? (ic * 11) >> 5 : (ic >> 3);  // /3 or /8, ic<=11
    const int tt = ic - gq * tpg;
    const int it = tt * 16 + mrow;
    int2 pr = make_int2(0, 0);
    if (it < P) {
      const int g2 = gbase + wave + 4 * gq;
      pr = ((const int2*)ids)[(size_t)g2 * P + it];
    }
    idreg = pr;
  };
  auto issue_gather = [&]() __attribute__((always_inline)) {
    const int iid = idreg.x;
    rid = idreg.y;
    pm = iid > 0 ? 1.f : 0.f;
    const float* ib = item_table + (size_t)iid * 64 + quad * 8;
    pf[0] = ((const float4*)ib)[0];
    pf[1] = ((const float4*)ib)[1];
    pf[2] = ((const float4*)(ib + 32))[0];
    pf[3] = ((const float4*)(ib + 32))[1];
  };
  load_ids(0); issue_gather();
  load_ids(1);

  // ---- P1: sV via register accumulation, column-coalesced global reads ----
  // Wave w owns groups g = w + 4*gi  ->  sV rows are self-produced; the
  // main loop reads only its own rows => NO barrier needed for sV.
  {
    const float* acol = atti_W1 + 64 * 64;  // rows 64..127 (user half)
    for (int gi = 0; gi < nGrp; ++gi) {
      const int g = wave + 4 * gi;
      const float* urow = user_table + (size_t)uidp[gbase + g] * 64;
      float v = 0.f;
#pragma unroll 8
      for (int k = 0; k < 64; ++k)
        v = fmaf(urow[k], acol[k * 64 + lane], v);
      sV[g * 64 + lane] = v;
    }
  }

  // ---- P2a: W1T(item)/W2T f16 staging + sR1 (= R1 + b1) + cst partials ----
  {
    for (int o = tid; o < 1024; o += 256) {  // W1T[n][k], k in 0..63 (item)
      const int k = o >> 4, fb = o & 15;
      const float4 v = ((const float4*)(gv_W1 + k * 64))[fb];
      const float* vp = (const float*)&v;
#pragma unroll
      for (int c = 0; c < 4; ++c) {
        const int n = fb * 4 + c;
        *(_Float16*)(smem + OFF_W1T + n * 128 + ((((k >> 3) ^ (n & 7))) << 4) +
                     ((k & 7) << 1)) = (_Float16)vp[c];
      }
    }
    for (int o = tid; o < 1024; o += 256) {  // W2T[n2][h]
      const int h = o >> 4, fb = o & 15;
      const float4 v = ((const float4*)(gv_W2 + h * 64))[fb];
      const float* vp = (const float*)&v;
#pragma unroll
      for (int c = 0; c < 4; ++c) {
        const int n = fb * 4 + c;
        *(_Float16*)(smem + OFF_W2T + n * 128 + ((((h >> 3) ^ (n & 7))) << 4) +
                     ((h & 7) << 1)) = (_Float16)vp[c];
      }
    }
    // sR1 f32: R1[r][n] = rate_r . W1[64:,n] + b1[n] (b1 folded; exact),
    // pitch 68 floats (bank-spread); coalesced gv_W1 column reads.
    {
      float* sR1 = (float*)(smem + OFF_R1);
      for (int o = tid; o < 384; o += 256) {
        const int r = o >> 6, n = o & 63;
        float s = gv_b1[n];
#pragma unroll 8
        for (int k = 0; k < 64; ++k)
          s = fmaf(rate_table[r * 64 + k], gv_W1[(64 + k) * 64 + n], s);
        sR1[r * 68 + n] = s;
      }
    }
    float* sCstP = (float*)(smem + OFF_U);
    const int n = tid & 63, jh = tid >> 6;
    float p = 0.f;
#pragma unroll 4
    for (int jj = 0; jj < 16; ++jj) {
      const int j = jh * 16 + jj;
      p = fmaf(gv_b2[j], atti_W1[j * 64 + n], p);
    }
    sCstP[jh * 64 + n] = p;
  }
  // per-lane constant preloads (global, L2-hot)
  float b2v[4], aw2v[4];
#pragma unroll
  for (int nt = 0; nt < 4; ++nt) {
    b2v[nt] = gv_b2[nt * 16 + mrow];
    aw2v[nt] = atti_W2[nt * 16 + mrow];
  }
  const float ab2 = atti_b2[0];

  __syncthreads();  // B3: W1T/W2T/cstP/sR1 ready (cross-wave)

  // ---- hoist W1 A-frags (item k-halves) BEFORE P2b (merges old B4/B5) ----
  f16x8 aW[4][2];
#pragma unroll
  for (int nt = 0; nt < 4; ++nt) {
#pragma unroll
    for (int ks = 0; ks < 2; ++ks)
      aW[nt][ks] = *(const f16x8*)(smem + OFF_W1T + (nt * 16 + mrow) * 128 +
                                   (((ks * 4 + quad) ^ (mrow & 7)) << 4));
  }

  // ---- P2b: M2T via MFMA (A,B from L2-hot global) + cstv to registers ----
  float cstv[4];
  {
    f16x8 aM[2];
#pragma unroll
    for (int ks = 0; ks < 2; ++ks) {
      f16x8 t;
#pragma unroll
      for (int j = 0; j < 8; ++j)
        t[j] = (_Float16)atti_W1[(ks * 32 + quad * 8 + j) * 64 + (wave * 16 + mrow)];
      aM[ks] = t;
    }
#pragma unroll
    for (int ht = 0; ht < 4; ++ht) {
      f32x4 c = {0.f, 0.f, 0.f, 0.f};
#pragma unroll
      for (int ks = 0; ks < 2; ++ks) {
        const float* s = gv_W2 + (ht * 16 + mrow) * 64 + ks * 32 + quad * 8;
        f16x8 b;
#pragma unroll
        for (int j = 0; j < 8; ++j) b[j] = (_Float16)s[j];
        c = __builtin_amdgcn_mfma_f32_16x16x32_f16(aM[ks], b, c, 0, 0, 0);
      }
      const int h = ht * 16 + mrow;
#pragma unroll
      for (int rg = 0; rg < 4; ++rg) {
        const int n3 = wave * 16 + quad * 4 + rg;
        *(_Float16*)(smem + OFF_M2T + n3 * 128 + ((((h >> 3) ^ (n3 & 7))) << 4) +
                     ((h & 7) << 1)) = (_Float16)c[rg];
      }
    }
    const float* sCstP = (const float*)(smem + OFF_U);
#pragma unroll
    for (int nt = 0; nt < 4; ++nt) {
      const int n = nt * 16 + mrow;
      cstv[nt] = atti_b1[n] + sCstP[n] + sCstP[64 + n] + sCstP[128 + n] +
                 sCstP[192 + n];
    }
  }
  __syncthreads();  // B4: M2T ready + hoists done; region A becomes H slots

  // =================== barrier-free main loop (R18 verbatim) ===================
  const float* sR1 = (const float*)(smem + OFF_R1);
  float vv[4], pnum[4], pden = 0.f;
  for (int idx = 0; idx < nIdx; ++idx) {
    const int gq = isS ? (idx * 11) >> 5 : (idx >> 3);
    const int tt = idx - gq * tpg;
    const int g = wave + 4 * gq;
    if (tt == 0) {
#pragma unroll
      for (int nt = 0; nt < 4; ++nt) {
        vv[nt] = sV[g * 64 + nt * 16 + mrow];
        pnum[nt] = 0.f;
      }
      pden = 0.f;
    }
    // In B-frags straight from prefetched registers (no LDS)
    f16x8 bIn0 = cvt_f16x8(pf[0], pf[1]);
    f16x8 bIn1 = cvt_f16x8(pf[2], pf[3]);
    const unsigned long long mball = __ballot(pm > 0.5f);
    const int ridcur = rid;
    issue_gather();      // gather for tile idx+1 (ids in idreg)
    load_ids(idx + 2);   // ids for tile idx+2 -> idreg
    // ---- layer1 (transposed): H^T -> b64 writes to wave-private slot ----
#pragma unroll
    for (int nt = 0; nt < 4; ++nt) {
      f32x4 c = {0.f, 0.f, 0.f, 0.f};
      c = __builtin_amdgcn_mfma_f32_16x16x32_f16(aW[nt][0], bIn0, c, 0, 0, 0);
      c = __builtin_amdgcn_mfma_f32_16x16x32_f16(aW[nt][1], bIn1, c, 0, 0, 0);
      const float4 r1q = *(const float4*)(sR1 + ridcur * 68 + nt * 16 + quad * 4);
      const float* r1p = (const float*)&r1q;
      f16x4 hv;
#pragma unroll
      for (int rg = 0; rg < 4; ++rg)
        hv[rg] = (_Float16)fmaxf(c[rg] + r1p[rg], 0.f);
      *(f16x4*)(smXw + mrow * 128 +
                (((nt * 2 + (quad >> 1)) ^ (mrow & 7)) << 4) +
                ((quad & 1) << 3)) = hv;
    }
    // ---- H A-frags for layer2 + attention ----
    f16x8 a2[2];
#pragma unroll
    for (int ks = 0; ks < 2; ++ks)
      a2[ks] = *(const f16x8*)(smXw + mrow * 128 +
                               (((ks * 4 + quad) ^ (mrow & 7)) << 4));
    float mk[4];
#pragma unroll
    for (int rg = 0; rg < 4; ++rg)
      mk[rg] = (float)((mball >> (quad * 4 + rg)) & 1ULL);
    // d-path first (attention logits); c-path MFMAs are e-independent
    float tl[4] = {0.f, 0.f, 0.f, 0.f};
#pragma unroll
    for (int nt = 0; nt < 4; ++nt) {
      f32x4 d = {0.f, 0.f, 0.f, 0.f};
#pragma unroll
      for (int ks = 0; ks < 2; ++ks) {
        const f16x8 bM = *(const f16x8*)(smem + OFF_M2T + (nt * 16 + mrow) * 128 +
                                         (((ks * 4 + quad) ^ (mrow & 7)) << 4));
        d = __builtin_amdgcn_mfma_f32_16x16x32_f16(a2[ks], bM, d, 0, 0, 0);
      }
#pragma unroll
      for (int rg = 0; rg < 4; ++rg) {
        const float hh = fmaxf(d[rg] + cstv[nt] + mk[rg] * vv[nt], 0.f);
        tl[rg] = fmaf(hh, aw2v[nt], tl[rg]);
      }
    }
    float e[4];
#pragma unroll
    for (int rg = 0; rg < 4; ++rg) {
      float t = tl[rg];
      t = qpx1_add(t);          // xor-1 via DPP quad_perm (VALU)
      t = qpx2_add(t);          // xor-2 via DPP quad_perm (VALU)
      t += __shfl_xor(t, 4); t += __shfl_xor(t, 8);
      e[rg] = __expf(t + ab2) * mk[rg];
      pden += e[rg];
    }
    // c-path (x2) consumed straight into pnum (b2 folded at flush)
#pragma unroll
    for (int nt = 0; nt < 4; ++nt) {
      f32x4 c = {0.f, 0.f, 0.f, 0.f};
#pragma unroll
      for (int ks = 0; ks < 2; ++ks) {
        const f16x8 bW = *(const f16x8*)(smem + OFF_W2T + (nt * 16 + mrow) * 128 +
                                         (((ks * 4 + quad) ^ (mrow & 7)) << 4));
        c = __builtin_amdgcn_mfma_f32_16x16x32_f16(a2[ks], bW, c, 0, 0, 0);
      }
      pnum[nt] = fmaf(e[0], c[0], pnum[nt]);
      pnum[nt] = fmaf(e[1], c[1], pnum[nt]);
      pnum[nt] = fmaf(e[2], c[2], pnum[nt]);
      pnum[nt] = fmaf(e[3], c[3], pnum[nt]);
    }
    if (tt == tpg - 1) {
      // ---- group flush (wave-local): quad-reduce + agg matvec + store ----
      float dsum = pden;
      dsum += __shfl_xor(dsum, 16); dsum += __shfl_xor(dsum, 32);
      const float rd = 1.f / (dsum + EPSV);
#pragma unroll
      for (int nt = 0; nt < 4; ++nt) {
        float s = pnum[nt];
        s += __shfl_xor(s, 16); s += __shfl_xor(s, 32);
        if (quad == 0) csW[nt * 16 + mrow] = (s + b2v[nt] * dsum) * rd;
      }
      float acc = agg_b[lane];
#pragma unroll 8
      for (int k = 0; k < 64; ++k) acc = fmaf(csW[k], agg_W[k * 64 + lane], acc);
      out[(size_t)(gbase + g) * 64 + lane] = fmaxf(acc, 0.f);
    }
  }
}

// ---------------- stage2 LDS layout (bytes) ----------------
#define S2_W1T 0       // 17408: attu_W1^T f16 [n][k], pitch 272 (bank-rotated)
#define S2_X   17408   // 8704:  2 waves x 16 rows x 272B
#define S2_E   26112   // 128:   2 x 16 f32
#define S2_MSK 26240   // 128:   2 x 16 f32
#define S2_HB  26368   // 1536:  2 x 192 f32 (concat/hidden ping-pong)
#define S2_SZ  27904

// ---------------------------------------------------------------------------
// Kernel 2: beta attention (MFMA) + h_iS + final 3-layer MLP.
// 256 blocks x 128 thr; wave w handles b = blockIdx*2 + w autonomously.
// ---------------------------------------------------------------------------
__global__ __launch_bounds__(128, 2) void stage2_kernel(
    const int* __restrict__ u_user_pad, const float* __restrict__ user_table,
    const float* __restrict__ hoI, const float* __restrict__ hiI,
    const float* __restrict__ attu_W1, const float* __restrict__ attu_b1,
    const float* __restrict__ attu_W2, const float* __restrict__ attu_b2,
    const float* __restrict__ aggn_W, const float* __restrict__ aggn_b,
    const float* __restrict__ cm_W1, const float* __restrict__ cm_b1,
    const float* __restrict__ cm_W2, const float* __restrict__ cm_b2,
    const float* __restrict__ cm_W3, const float* __restrict__ cm_b3,
    float* __restrict__ out) {
  __shared__ __align__(16) char smem[S2_SZ];
  const int tid = threadIdx.x;
  const int wave = tid >> 6, lane = tid & 63;
  const int quad = lane >> 4, mrow = lane & 15;
  const int b = (int)blockIdx.x * 2 + wave;

  char* sW1 = smem + S2_W1T;
  char* sXw = smem + S2_X + wave * 4352;
  float* sE = (float*)(smem + S2_E) + wave * 16;
  float* sM = (float*)(smem + S2_MSK) + wave * 16;
  float* sB = (float*)(smem + S2_HB) + wave * 192;

  for (int o = tid; o < 2048; o += 128) {
    const int k = o >> 4, fb = o & 15;
    const float4 v = ((const float4*)(attu_W1 + k * 64))[fb];
    const float* vp = (const float*)&v;
#pragma unroll
    for (int c = 0; c < 4; ++c) {
      const int n = fb * 4 + c;
      *(_Float16*)(sW1 + n * 272 + ((k >> 3) << 4) + ((k & 7) << 1)) = (_Float16)vp[c];
    }
  }
  float b1v[4], w2v[4];
#pragma unroll
  for (int nt = 0; nt < 4; ++nt) {
    b1v[nt] = attu_b1[nt * 16 + mrow];
    w2v[nt] = attu_W2[nt * 16 + mrow];
  }
  const float b2s = attu_b2[0];

  float4 pa[4], pb[4];
  float msk[4];
  auto pf = [&](int tt) __attribute__((always_inline)) {
#pragma unroll
    for (int k = 0; k < 4; ++k) {
      const int u = lane + (k << 6);
      const int r = u >> 4, bb = u & 15;
      const int q = tt * 16 + r;
      const int qc = q < 40 ? q : 39;
      int uid = 0;
      float m = 0.f;
      if (q < 40) {
        uid = u_user_pad[b * 40 + q];
        m = uid > 0 ? 1.f : 0.f;
      }
      msk[k] = m;
      const float* src = (bb < 8)
                             ? hoI + ((size_t)b * 40 + qc) * 64 + bb * 8
                             : user_table + (size_t)uid * 64 + (bb - 8) * 8;
      pa[k] = ((const float4*)src)[0];
      pb[k] = ((const float4*)src)[1];
    }
  };
  pf(0);
  __syncthreads();  // W1T ready

  float numer = 0.f, pden = 0.f;
  for (int tt = 0; tt < 3; ++tt) {
#pragma unroll
    for (int k = 0; k < 4; ++k) {
      const int u = lane + (k << 6);
      const int r = u >> 4, bb = u & 15;
      *(f16x8*)(sXw + r * 272 + (bb << 4)) = cvt_f16x8(pa[k], pb[k]);
      if (bb == 0) sM[r] = msk[k];
    }
    if (tt < 2) pf(tt + 1);
    f16x8 a[4];
#pragma unroll
    for (int ks = 0; ks < 4; ++ks)
      a[ks] = *(const f16x8*)(sXw + mrow * 272 + ((ks * 4 + quad) << 4));
    float mk[4];
#pragma unroll
    for (int rg = 0; rg < 4; ++rg) mk[rg] = sM[quad * 4 + rg];
    float tl[4] = {0.f, 0.f, 0.f, 0.f};
#pragma unroll
    for (int nt = 0; nt < 4; ++nt) {
      f32x4 d = {0.f, 0.f, 0.f, 0.f};
      const int n = nt * 16 + mrow;
#pragma unroll
      for (int ks = 0; ks < 4; ++ks) {
        const f16x8 bW = *(const f16x8*)(sW1 + n * 272 + ((ks * 4 + quad) << 4));
        d = __builtin_amdgcn_mfma_f32_16x16x32_f16(a[ks], bW, d, 0, 0, 0);
      }
#pragma unroll
      for (int rg = 0; rg < 4; ++rg) {
        const float h = fmaxf(d[rg] + b1v[nt], 0.f);
        tl[rg] = fmaf(h, w2v[nt], tl[rg]);
      }
    }
    float e[4];
#pragma unroll
    for (int rg = 0; rg < 4; ++rg) {
      float t = tl[rg];
      t = qpx1_add(t);
      t = qpx2_add(t);
      t += __shfl_xor(t, 4); t += __shfl_xor(t, 8);
      e[rg] = __expf(t + b2s) * mk[rg];
      pden += e[rg];
    }
    if (mrow == 0) {
#pragma unroll
      for (int rg = 0; rg < 4; ++rg) sE[quad * 4 + rg] = e[rg];
    }
#pragma unroll 4
    for (int r = 0; r < 16; ++r) {
      const float er = sE[r];
      const float xv = (float)*(const _Float16*)(sXw + r * 272 + ((lane >> 3) << 4) +
                                                 ((lane & 7) << 1));
      numer = fmaf(er, xv, numer);
    }
  }
  pden += __shfl_xor(pden, 16);
  pden += __shfl_xor(pden, 32);
  const float hagg = numer / (pden + EPSV);

  sB[128 + lane] = hagg;
  sB[lane] = hiI[(size_t)b * 64 + lane];
  float acc = aggn_b[lane];
#pragma unroll 8
  for (int k = 0; k < 64; ++k) acc = fmaf(sB[128 + k], aggn_W[k * 64 + lane], acc);
  sB[64 + lane] = fmaxf(acc, 0.f);
  float c1 = cm_b1[lane];
#pragma unroll 8
  for (int k = 0; k < 128; ++k) c1 = fmaf(sB[k], cm_W1[k * 64 + lane], c1);
  sB[128 + lane] = fmaxf(c1, 0.f);
  float c2 = cm_b2[lane];
#pragma unroll 8
  for (int k = 0; k < 64; ++k) c2 = fmaf(sB[128 + k], cm_W2[k * 64 + lane], c2);
  sB[lane] = fmaxf(c2, 0.f);
  float c3 = cm_b3[lane];
#pragma unroll 8
  for (int k = 0; k < 64; ++k) c3 = fmaf(sB[k], cm_W3[k * 64 + lane], c3);
  out[(size_t)b * 64 + lane] = fmaxf(c3, 0.f);
}

extern "C" void kernel_launch(void* const* d_in, const int* in_sizes, int n_in,
                              void* d_out, int out_size, void* d_ws, size_t ws_size,
                              hipStream_t stream) {
  const int* uids = (const int*)d_in[0];
  const int* u_item_pad = (const int*)d_in[1];
  const int* u_user_pad = (const int*)d_in[2];
  const int* u_user_item_pad = (const int*)d_in[3];
  const float* user_table = (const float*)d_in[4];
  const float* item_table = (const float*)d_in[5];
  const float* rate_table = (const float*)d_in[6];
  const float* gv_W1 = (const float*)d_in[7];
  const float* gv_b1 = (const float*)d_in[8];
  const float* gv_W2 = (const float*)d_in[9];
  const float* gv_b2 = (const float*)d_in[10];
  const float* atti_W1 = (const float*)d_in[11];
  const float* atti_b1 = (const float*)d_in[12];
  const float* atti_W2 = (const float*)d_in[13];
  const float* atti_b2 = (const float*)d_in[14];
  const float* agg_W = (const float*)d_in[15];
  const float* agg_b = (const float*)d_in[16];
  const float* attu_W1 = (const float*)d_in[17];
  const float* attu_b1 = (const float*)d_in[18];
  const float* attu_W2 = (const float*)d_in[19];
  const float* attu_b2 = (const float*)d_in[20];
  const float* aggn_W = (const float*)d_in[21];
  const float* aggn_b = (const float*)d_in[22];
  const float* cm_W1 = (const float*)d_in[23];
  const float* cm_b1 = (const float*)d_in[24];
  const float* cm_W2 = (const float*)d_in[25];
  const float* cm_b2 = (const float*)d_in[26];
  const float* cm_W3 = (const float*)d_in[27];
  const float* cm_b3 = (const float*)d_in[28];
  float* out = (float*)d_out;

  float* hoI = (float*)d_ws;                 // 512*40*64 floats
  float* hiI = hoI + (size_t)512 * 40 * 64;  // 512*64 floats

  // Merged I (128 blocks x 4 groups, dispatched first) + S (1280 x 16).
  agg_kernel<<<128 + 1280, 256, 0, stream>>>(
      128, u_user_item_pad, u_user_pad, u_item_pad, uids,
      user_table, item_table, rate_table,
      gv_W1, gv_b1, gv_W2, gv_b2,
      atti_W1, atti_b1, atti_W2, atti_b2,
      agg_W, agg_b, hoI, hiI);
  // Beta attention + h_iS + final MLP (wave-autonomous MFMA).
  stage2_kernel<<<256, 128, 0, stream>>>(u_user_pad, user_table, hoI, hiI,
                                         attu_W1, attu_b1, attu_W2, attu_b2,
                                         aggn_W, aggn_b,
                                         cm_W1, cm_b1, cm_W2, cm_b2, cm_W3, cm_b3,
                                         out);
}

// Round 14
// 242.000 us; speedup vs baseline: 1.1442x; 1.1442x over previous
//
#include <hip/hip_runtime.h>
#include <math.h>

#define EPSV 1e-10f

typedef _Float16 f16x8 __attribute__((ext_vector_type(8)));
typedef _Float16 f16x4 __attribute__((ext_vector_type(4)));
typedef float f32x4 __attribute__((ext_vector_type(4)));

// ---------------- agg LDS layout (bytes), R20 (32KB) ----------------
// A (0..8192):      W1T f16 [64][128] swz (copied from img) -> 4 wave-private
//                   H slots (wave*2048) in main loop; csW at flush.
// B (8192..16384):  W2T image (copied)
// C (16384..24576): M2T image (copied)
// AU f32 [64][64] = 16KB overlays B+C during P0/P1 (dead before copy).
// D (24576..28672): uS f32 16x64 (P0/P1) -> cst (24576..24832) + sR1
//                   (25856..27488) after the image copy.
// E (28672..32768): sV[g][n], g < 16
// The 28KB weight image in workspace is laid out byte-identically to LDS
// [0, 28672), so the prologue staging collapses to ONE coalesced copy.
#define OFF_W1T  0
#define OFF_AU   8192
#define OFF_W2T  8192
#define OFF_M2T  16384
#define OFF_U    24576
#define OFF_CST  24576
#define OFF_R1   25856
#define OFF_V    28672
#define SMEM_SZ  32768
#define IMG_SZ   28672

__device__ __forceinline__ f16x8 cvt_f16x8(const float4 a, const float4 b) {
  f16x8 h;
  h[0] = (_Float16)a.x; h[1] = (_Float16)a.y; h[2] = (_Float16)a.z; h[3] = (_Float16)a.w;
  h[4] = (_Float16)b.x; h[5] = (_Float16)b.y; h[6] = (_Float16)b.z; h[7] = (_Float16)b.w;
  return h;
}

// DPP quad_perm adds: exact xor-1 / xor-2 cross-lane sums at VALU speed.
__device__ __forceinline__ float qpx1_add(float x) {
  return x + __int_as_float(__builtin_amdgcn_update_dpp(
                 0, __float_as_int(x), 0xB1, 0xF, 0xF, false));
}
__device__ __forceinline__ float qpx2_add(float x) {
  return x + __int_as_float(__builtin_amdgcn_update_dpp(
                 0, __float_as_int(x), 0x4E, 0xF, 0xF, false));
}

// ---------------------------------------------------------------------------
// prep_kernel: computes the block-invariant weight image ONCE (previously
// recomputed by all 1408 agg blocks). 5 blocks x 256 thr, one phase each:
//  0: W1T f16 swz   (img + 0)
//  1: W2T f16 swz   (img + 8192)
//  2: M2T f16 swz   (img + 16384)  [MFMA, 4 waves]
//  3: sR1 = R1 + b1 (img + 25856)  f32 [6][68]
//  4: cst = atti_b1 + gv_b2 . atti_W1  (img + 24576) f32 [64]
// ---------------------------------------------------------------------------
__global__ __launch_bounds__(256, 2) void prep_kernel(
    const float* __restrict__ rate_table,
    const float* __restrict__ gv_W1, const float* __restrict__ gv_b1,
    const float* __restrict__ gv_W2, const float* __restrict__ gv_b2,
    const float* __restrict__ atti_W1, const float* __restrict__ atti_b1,
    char* __restrict__ img) {
  const int tid = threadIdx.x;
  const int wave = tid >> 6, lane = tid & 63;
  const int quad = lane >> 4, mrow = lane & 15;
  const int phase = (int)blockIdx.x;

  if (phase == 0) {  // W1T[n][k], k in 0..63 (item half of gv_W1)
    for (int o = tid; o < 1024; o += 256) {
      const int k = o >> 4, fb = o & 15;
      const float4 v = ((const float4*)(gv_W1 + k * 64))[fb];
      const float* vp = (const float*)&v;
#pragma unroll
      for (int c = 0; c < 4; ++c) {
        const int n = fb * 4 + c;
        *(_Float16*)(img + n * 128 + ((((k >> 3) ^ (n & 7))) << 4) +
                     ((k & 7) << 1)) = (_Float16)vp[c];
      }
    }
  } else if (phase == 1) {  // W2T[n2][h]
    for (int o = tid; o < 1024; o += 256) {
      const int h = o >> 4, fb = o & 15;
      const float4 v = ((const float4*)(gv_W2 + h * 64))[fb];
      const float* vp = (const float*)&v;
#pragma unroll
      for (int c = 0; c < 4; ++c) {
        const int n = fb * 4 + c;
        *(_Float16*)(img + 8192 + n * 128 + ((((h >> 3) ^ (n & 7))) << 4) +
                     ((h & 7) << 1)) = (_Float16)vp[c];
      }
    }
  } else if (phase == 2) {  // M2T = W2 . AW1x via MFMA (4 waves cover n3)
    f16x8 aM[2];
#pragma unroll
    for (int ks = 0; ks < 2; ++ks) {
      f16x8 t;
#pragma unroll
      for (int j = 0; j < 8; ++j)
        t[j] = (_Float16)atti_W1[(ks * 32 + quad * 8 + j) * 64 + (wave * 16 + mrow)];
      aM[ks] = t;
    }
#pragma unroll
    for (int ht = 0; ht < 4; ++ht) {
      f32x4 c = {0.f, 0.f, 0.f, 0.f};
#pragma unroll
      for (int ks = 0; ks < 2; ++ks) {
        const float* s = gv_W2 + (ht * 16 + mrow) * 64 + ks * 32 + quad * 8;
        f16x8 b;
#pragma unroll
        for (int j = 0; j < 8; ++j) b[j] = (_Float16)s[j];
        c = __builtin_amdgcn_mfma_f32_16x16x32_f16(aM[ks], b, c, 0, 0, 0);
      }
      const int h = ht * 16 + mrow;
#pragma unroll
      for (int rg = 0; rg < 4; ++rg) {
        const int n3 = wave * 16 + quad * 4 + rg;
        *(_Float16*)(img + 16384 + n3 * 128 + ((((h >> 3) ^ (n3 & 7))) << 4) +
                     ((h & 7) << 1)) = (_Float16)c[rg];
      }
    }
  } else if (phase == 3) {  // sR1[r][n] = rate_r . W1[64:,n] + b1[n]
    float* sR1 = (float*)(img + OFF_R1);
    for (int o = tid; o < 384; o += 256) {
      const int r = o >> 6, n = o & 63;
      float s = gv_b1[n];
#pragma unroll 8
      for (int k = 0; k < 64; ++k)
        s = fmaf(rate_table[r * 64 + k], gv_W1[(64 + k) * 64 + n], s);
      sR1[r * 68 + n] = s;
    }
  } else {  // cst[n] = atti_b1[n] + sum_j gv_b2[j] * atti_W1[j][n]
    if (tid < 64) {
      float p = atti_b1[tid];
#pragma unroll 8
      for (int j = 0; j < 64; ++j) p = fmaf(gv_b2[j], atti_W1[j * 64 + tid], p);
      ((float*)(img + OFF_CST))[tid] = p;
    }
  }
}

// ---------------------------------------------------------------------------
// Fused item-aggregation. I-blocks FIRST [0,nIblk): 4 groups (P=100, 1/wave);
// S-blocks after: 16 groups (P=40, 4/wave). 256 thr = 4 waves.
// R20: prologue amortization. R19 proved prologue edits move dur by ~10us
// (it IS a major term) but the register-P1 was the wrong implementation.
// R20 keeps R18's proven P0/P1 (staged AU + LDS dot) and replaces ALL the
// block-invariant staging compute (W1T/W2T f16 scatter, sR1 384x64 fmaf,
// cstP, and the whole P2b MFMA phase) with ONE 28KB coalesced copy from a
// precomputed workspace image (L2-resident across blocks). Barriers 5 -> 4.
// Main loop = R18 verbatim (ballot mask + DPP reduce, best known: 266us).
// Tripwires: FETCH ~101MB / WRITE ~5.2MB / VGPR ~76 / conflicts ~3.5M.
// ---------------------------------------------------------------------------
__global__ __launch_bounds__(256, 3) void agg_kernel(
    const int nIblk,
    const int* __restrict__ idsS, const int* __restrict__ uidS,
    const int* __restrict__ idsI, const int* __restrict__ uidI,
    const float* __restrict__ user_table, const float* __restrict__ item_table,
    const float* __restrict__ atti_W1,
    const float* __restrict__ gv_b2, const float* __restrict__ atti_W2,
    const float* __restrict__ atti_b2,
    const float* __restrict__ agg_W, const float* __restrict__ agg_b,
    const char* __restrict__ img,
    float* __restrict__ outS, float* __restrict__ outI) {
  __shared__ __align__(16) char smem[SMEM_SZ];
  const int tid = threadIdx.x;
  const int wave = tid >> 6, lane = tid & 63;
  const int quad = lane >> 4, mrow = lane & 15;

  const bool isS = (int)blockIdx.x >= nIblk;
  const int NG = isS ? 16 : 4;
  const int P = isS ? 40 : 100;
  const int nGrp = isS ? 4 : 1;  // groups per wave
  const int tpg = isS ? 3 : 8;   // 16-row tiles per group
  const int nIdx = nGrp * tpg;   // 12 or 8
  const int* __restrict__ ids = isS ? idsS : idsI;
  const int* __restrict__ uidp = isS ? uidS : uidI;
  float* __restrict__ out = isS ? outS : outI;
  const int gbase = isS ? ((int)blockIdx.x - nIblk) * 16 : (int)blockIdx.x * 4;

  float* sV = (float*)(smem + OFF_V);
  char* smXw = smem + OFF_W1T + wave * 2048;  // wave-private H slot (post-B4)
  float* csW = (float*)smXw;                  // epilogue c vector (H dead then)

  // ---- gather prefetch pipeline (issued FIRST; hides under prologue) ----
  const int nIdxM1 = nIdx - 1;
  int2 idreg;
  float4 pf[4];
  float pm;
  int rid;
  auto load_ids = [&](int idx) __attribute__((always_inline)) {
    const int ic = idx < nIdxM1 ? idx : nIdxM1;  // clamp (tail prefetch harmless)
    const int gq = isS ? (ic * 11) >> 5 : (ic >> 3);  // /3 or /8, ic<=11
    const int tt = ic - gq * tpg;
    const int it = tt * 16 + mrow;
    int2 pr = make_int2(0, 0);
    if (it < P) {
      const int g2 = gbase + wave + 4 * gq;
      pr = ((const int2*)ids)[(size_t)g2 * P + it];
    }
    idreg = pr;
  };
  auto issue_gather = [&]() __attribute__((always_inline)) {
    const int iid = idreg.x;
    rid = idreg.y;
    pm = iid > 0 ? 1.f : 0.f;
    const float* ib = item_table + (size_t)iid * 64 + quad * 8;
    pf[0] = ((const float4*)ib)[0];
    pf[1] = ((const float4*)ib)[1];
    pf[2] = ((const float4*)(ib + 32))[0];
    pf[3] = ((const float4*)(ib + 32))[1];
  };
  load_ids(0); issue_gather();
  load_ids(1);

  // ---- P0: uS (region D) + AU = AW1u^T f32 (overlay on B+C, f4-swizzled) ----
  {
    float* uS = (float*)(smem + OFF_U);
    float* AU = (float*)(smem + OFF_AU);
    for (int t = tid; t < NG * 64; t += 256) {
      const int g = t >> 6, f = t & 63;
      uS[t] = user_table[(size_t)uidp[gbase + g] * 64 + f];
    }
    for (int o = tid; o < 1024; o += 256) {  // AU[j][k] = atti_W1[64+k][j]
      const int k = o >> 4, fb = o & 15;
      const float4 v = ((const float4*)(atti_W1 + (64 + k) * 64))[fb];
      const float* vp = (const float*)&v;
#pragma unroll
      for (int c = 0; c < 4; ++c) {
        const int j = fb * 4 + c;
        AU[j * 64 + (((k >> 2) ^ (j & 15)) << 2) + (k & 3)] = vp[c];
      }
    }
  }
  __syncthreads();  // B1
  // ---- P1: v[g][j] = u[g] . AW1u[:,j] ----
  {
    const float4* u4 = (const float4*)(smem + OFF_U);
    const float4* a4 = (const float4*)(smem + OFF_AU);
    for (int t = tid; t < NG * 64; t += 256) {
      const int g = t >> 6, j = t & 63;
      float s = 0.f;
#pragma unroll 4
      for (int kb = 0; kb < 16; ++kb) {
        const float4 uu = u4[g * 16 + kb];
        const float4 aa = a4[j * 16 + (kb ^ (j & 15))];
        s += uu.x * aa.x + uu.y * aa.y + uu.z * aa.z + uu.w * aa.w;
      }
      sV[t] = s;
    }
  }
  __syncthreads();  // B2: uS/AU dead
  // ---- image copy: 28KB, byte-identical layout -> 7 float4 per thread ----
  {
    const float4* src = (const float4*)img;
    float4* dst = (float4*)smem;
#pragma unroll
    for (int o = 0; o < 7; ++o) dst[tid + o * 256] = src[tid + o * 256];
  }
  // per-lane constant preloads (global, L2-hot)
  float b2v[4], aw2v[4];
#pragma unroll
  for (int nt = 0; nt < 4; ++nt) {
    b2v[nt] = gv_b2[nt * 16 + mrow];
    aw2v[nt] = atti_W2[nt * 16 + mrow];
  }
  const float ab2 = atti_b2[0];
  __syncthreads();  // B3: images ready

  // ---- hoist W1 A-frags + cstv from the copied image ----
  f16x8 aW[4][2];
#pragma unroll
  for (int nt = 0; nt < 4; ++nt) {
#pragma unroll
    for (int ks = 0; ks < 2; ++ks)
      aW[nt][ks] = *(const f16x8*)(smem + OFF_W1T + (nt * 16 + mrow) * 128 +
                                   (((ks * 4 + quad) ^ (mrow & 7)) << 4));
  }
  float cstv[4];
  {
    const float* cst = (const float*)(smem + OFF_CST);
#pragma unroll
    for (int nt = 0; nt < 4; ++nt) cstv[nt] = cst[nt * 16 + mrow];
  }
  __syncthreads();  // B4: hoist done; region A becomes per-wave H slots

  // =================== barrier-free main loop (R18 verbatim) ===================
  const float* sR1 = (const float*)(smem + OFF_R1);
  float vv[4], pnum[4], pden = 0.f;
  for (int idx = 0; idx < nIdx; ++idx) {
    const int gq = isS ? (idx * 11) >> 5 : (idx >> 3);
    const int tt = idx - gq * tpg;
    const int g = wave + 4 * gq;
    if (tt == 0) {
#pragma unroll
      for (int nt = 0; nt < 4; ++nt) {
        vv[nt] = sV[g * 64 + nt * 16 + mrow];
        pnum[nt] = 0.f;
      }
      pden = 0.f;
    }
    // In B-frags straight from prefetched registers (no LDS)
    f16x8 bIn0 = cvt_f16x8(pf[0], pf[1]);
    f16x8 bIn1 = cvt_f16x8(pf[2], pf[3]);
    const unsigned long long mball = __ballot(pm > 0.5f);
    const int ridcur = rid;
    issue_gather();      // gather for tile idx+1 (ids in idreg)
    load_ids(idx + 2);   // ids for tile idx+2 -> idreg
    // ---- layer1 (transposed): H^T -> b64 writes to wave-private slot ----
#pragma unroll
    for (int nt = 0; nt < 4; ++nt) {
      f32x4 c = {0.f, 0.f, 0.f, 0.f};
      c = __builtin_amdgcn_mfma_f32_16x16x32_f16(aW[nt][0], bIn0, c, 0, 0, 0);
      c = __builtin_amdgcn_mfma_f32_16x16x32_f16(aW[nt][1], bIn1, c, 0, 0, 0);
      const float4 r1q = *(const float4*)(sR1 + ridcur * 68 + nt * 16 + quad * 4);
      const float* r1p = (const float*)&r1q;
      f16x4 hv;
#pragma unroll
      for (int rg = 0; rg < 4; ++rg)
        hv[rg] = (_Float16)fmaxf(c[rg] + r1p[rg], 0.f);
      *(f16x4*)(smXw + mrow * 128 +
                (((nt * 2 + (quad >> 1)) ^ (mrow & 7)) << 4) +
                ((quad & 1) << 3)) = hv;
    }
    // ---- H A-frags for layer2 + attention ----
    f16x8 a2[2];
#pragma unroll
    for (int ks = 0; ks < 2; ++ks)
      a2[ks] = *(const f16x8*)(smXw + mrow * 128 +
                               (((ks * 4 + quad) ^ (mrow & 7)) << 4));
    float mk[4];
#pragma unroll
    for (int rg = 0; rg < 4; ++rg)
      mk[rg] = (float)((mball >> (quad * 4 + rg)) & 1ULL);
    // d-path first (attention logits); c-path MFMAs are e-independent
    float tl[4] = {0.f, 0.f, 0.f, 0.f};
#pragma unroll
    for (int nt = 0; nt < 4; ++nt) {
      f32x4 d = {0.f, 0.f, 0.f, 0.f};
#pragma unroll
      for (int ks = 0; ks < 2; ++ks) {
        const f16x8 bM = *(const f16x8*)(smem + OFF_M2T + (nt * 16 + mrow) * 128 +
                                         (((ks * 4 + quad) ^ (mrow & 7)) << 4));
        d = __builtin_amdgcn_mfma_f32_16x16x32_f16(a2[ks], bM, d, 0, 0, 0);
      }
#pragma unroll
      for (int rg = 0; rg < 4; ++rg) {
        const float hh = fmaxf(d[rg] + cstv[nt] + mk[rg] * vv[nt], 0.f);
        tl[rg] = fmaf(hh, aw2v[nt], tl[rg]);
      }
    }
    float e[4];
#pragma unroll
    for (int rg = 0; rg < 4; ++rg) {
      float t = tl[rg];
      t = qpx1_add(t);          // xor-1 via DPP quad_perm (VALU)
      t = qpx2_add(t);          // xor-2 via DPP quad_perm (VALU)
      t += __shfl_xor(t, 4); t += __shfl_xor(t, 8);
      e[rg] = __expf(t + ab2) * mk[rg];
      pden += e[rg];
    }
    // c-path (x2) consumed straight into pnum (b2 folded at flush)
#pragma unroll
    for (int nt = 0; nt < 4; ++nt) {
      f32x4 c = {0.f, 0.f, 0.f, 0.f};
#pragma unroll
      for (int ks = 0; ks < 2; ++ks) {
        const f16x8 bW = *(const f16x8*)(smem + OFF_W2T + (nt * 16 + mrow) * 128 +
                                         (((ks * 4 + quad) ^ (mrow & 7)) << 4));
        c = __builtin_amdgcn_mfma_f32_16x16x32_f16(a2[ks], bW, c, 0, 0, 0);
      }
      pnum[nt] = fmaf(e[0], c[0], pnum[nt]);
      pnum[nt] = fmaf(e[1], c[1], pnum[nt]);
      pnum[nt] = fmaf(e[2], c[2], pnum[nt]);
      pnum[nt] = fmaf(e[3], c[3], pnum[nt]);
    }
    if (tt == tpg - 1) {
      // ---- group flush (wave-local): quad-reduce + agg matvec + store ----
      float dsum = pden;
      dsum += __shfl_xor(dsum, 16); dsum += __shfl_xor(dsum, 32);
      const float rd = 1.f / (dsum + EPSV);
#pragma unroll
      for (int nt = 0; nt < 4; ++nt) {
        float s = pnum[nt];
        s += __shfl_xor(s, 16); s += __shfl_xor(s, 32);
        if (quad == 0) csW[nt * 16 + mrow] = (s + b2v[nt] * dsum) * rd;
      }
      float acc = agg_b[lane];
#pragma unroll 8
      for (int k = 0; k < 64; ++k) acc = fmaf(csW[k], agg_W[k * 64 + lane], acc);
      out[(size_t)(gbase + g) * 64 + lane] = fmaxf(acc, 0.f);
    }
  }
}

// ---------------- stage2 LDS layout (bytes) ----------------
#define S2_W1T 0       // 17408: attu_W1^T f16 [n][k], pitch 272 (bank-rotated)
#define S2_X   17408   // 8704:  2 waves x 16 rows x 272B
#define S2_E   26112   // 128:   2 x 16 f32
#define S2_MSK 26240   // 128:   2 x 16 f32
#define S2_HB  26368   // 1536:  2 x 192 f32 (concat/hidden ping-pong)
#define S2_SZ  27904

// ---------------------------------------------------------------------------
// Kernel 2: beta attention (MFMA) + h_iS + final 3-layer MLP.
// 256 blocks x 128 thr; wave w handles b = blockIdx*2 + w autonomously.
// ---------------------------------------------------------------------------
__global__ __launch_bounds__(128, 2) void stage2_kernel(
    const int* __restrict__ u_user_pad, const float* __restrict__ user_table,
    const float* __restrict__ hoI, const float* __restrict__ hiI,
    const float* __restrict__ attu_W1, const float* __restrict__ attu_b1,
    const float* __restrict__ attu_W2, const float* __restrict__ attu_b2,
    const float* __restrict__ aggn_W, const float* __restrict__ aggn_b,
    const float* __restrict__ cm_W1, const float* __restrict__ cm_b1,
    const float* __restrict__ cm_W2, const float* __restrict__ cm_b2,
    const float* __restrict__ cm_W3, const float* __restrict__ cm_b3,
    float* __restrict__ out) {
  __shared__ __align__(16) char smem[S2_SZ];
  const int tid = threadIdx.x;
  const int wave = tid >> 6, lane = tid & 63;
  const int quad = lane >> 4, mrow = lane & 15;
  const int b = (int)blockIdx.x * 2 + wave;

  char* sW1 = smem + S2_W1T;
  char* sXw = smem + S2_X + wave * 4352;
  float* sE = (float*)(smem + S2_E) + wave * 16;
  float* sM = (float*)(smem + S2_MSK) + wave * 16;
  float* sB = (float*)(smem + S2_HB) + wave * 192;

  for (int o = tid; o < 2048; o += 128) {
    const int k = o >> 4, fb = o & 15;
    const float4 v = ((const float4*)(attu_W1 + k * 64))[fb];
    const float* vp = (const float*)&v;
#pragma unroll
    for (int c = 0; c < 4; ++c) {
      const int n = fb * 4 + c;
      *(_Float16*)(sW1 + n * 272 + ((k >> 3) << 4) + ((k & 7) << 1)) = (_Float16)vp[c];
    }
  }
  float b1v[4], w2v[4];
#pragma unroll
  for (int nt = 0; nt < 4; ++nt) {
    b1v[nt] = attu_b1[nt * 16 + mrow];
    w2v[nt] = attu_W2[nt * 16 + mrow];
  }
  const float b2s = attu_b2[0];

  float4 pa[4], pb[4];
  float msk[4];
  auto pf = [&](int tt) __attribute__((always_inline)) {
#pragma unroll
    for (int k = 0; k < 4; ++k) {
      const int u = lane + (k << 6);
      const int r = u >> 4, bb = u & 15;
      const int q = tt * 16 + r;
      const int qc = q < 40 ? q : 39;
      int uid = 0;
      float m = 0.f;
      if (q < 40) {
        uid = u_user_pad[b * 40 + q];
        m = uid > 0 ? 1.f : 0.f;
      }
      msk[k] = m;
      const float* src = (bb < 8)
                             ? hoI + ((size_t)b * 40 + qc) * 64 + bb * 8
                             : user_table + (size_t)uid * 64 + (bb - 8) * 8;
      pa[k] = ((const float4*)src)[0];
      pb[k] = ((const float4*)src)[1];
    }
  };
  pf(0);
  __syncthreads();  // W1T ready

  float numer = 0.f, pden = 0.f;
  for (int tt = 0; tt < 3; ++tt) {
#pragma unroll
    for (int k = 0; k < 4; ++k) {
      const int u = lane + (k << 6);
      const int r = u >> 4, bb = u & 15;
      *(f16x8*)(sXw + r * 272 + (bb << 4)) = cvt_f16x8(pa[k], pb[k]);
      if (bb == 0) sM[r] = msk[k];
    }
    if (tt < 2) pf(tt + 1);
    f16x8 a[4];
#pragma unroll
    for (int ks = 0; ks < 4; ++ks)
      a[ks] = *(const f16x8*)(sXw + mrow * 272 + ((ks * 4 + quad) << 4));
    float mk[4];
#pragma unroll
    for (int rg = 0; rg < 4; ++rg) mk[rg] = sM[quad * 4 + rg];
    float tl[4] = {0.f, 0.f, 0.f, 0.f};
#pragma unroll
    for (int nt = 0; nt < 4; ++nt) {
      f32x4 d = {0.f, 0.f, 0.f, 0.f};
      const int n = nt * 16 + mrow;
#pragma unroll
      for (int ks = 0; ks < 4; ++ks) {
        const f16x8 bW = *(const f16x8*)(sW1 + n * 272 + ((ks * 4 + quad) << 4));
        d = __builtin_amdgcn_mfma_f32_16x16x32_f16(a[ks], bW, d, 0, 0, 0);
      }
#pragma unroll
      for (int rg = 0; rg < 4; ++rg) {
        const float h = fmaxf(d[rg] + b1v[nt], 0.f);
        tl[rg] = fmaf(h, w2v[nt], tl[rg]);
      }
    }
    float e[4];
#pragma unroll
    for (int rg = 0; rg < 4; ++rg) {
      float t = tl[rg];
      t = qpx1_add(t);
      t = qpx2_add(t);
      t += __shfl_xor(t, 4); t += __shfl_xor(t, 8);
      e[rg] = __expf(t + b2s) * mk[rg];
      pden += e[rg];
    }
    if (mrow == 0) {
#pragma unroll
      for (int rg = 0; rg < 4; ++rg) sE[quad * 4 + rg] = e[rg];
    }
#pragma unroll 4
    for (int r = 0; r < 16; ++r) {
      const float er = sE[r];
      const float xv = (float)*(const _Float16*)(sXw + r * 272 + ((lane >> 3) << 4) +
                                                 ((lane & 7) << 1));
      numer = fmaf(er, xv, numer);
    }
  }
  pden += __shfl_xor(pden, 16);
  pden += __shfl_xor(pden, 32);
  const float hagg = numer / (pden + EPSV);

  sB[128 + lane] = hagg;
  sB[lane] = hiI[(size_t)b * 64 + lane];
  float acc = aggn_b[lane];
#pragma unroll 8
  for (int k = 0; k < 64; ++k) acc = fmaf(sB[128 + k], aggn_W[k * 64 + lane], acc);
  sB[64 + lane] = fmaxf(acc, 0.f);
  float c1 = cm_b1[lane];
#pragma unroll 8
  for (int k = 0; k < 128; ++k) c1 = fmaf(sB[k], cm_W1[k * 64 + lane], c1);
  sB[128 + lane] = fmaxf(c1, 0.f);
  float c2 = cm_b2[lane];
#pragma unroll 8
  for (int k = 0; k < 64; ++k) c2 = fmaf(sB[128 + k], cm_W2[k * 64 + lane], c2);
  sB[lane] = fmaxf(c2, 0.f);
  float c3 = cm_b3[lane];
#pragma unroll 8
  for (int k = 0; k < 64; ++k) c3 = fmaf(sB[k], cm_W3[k * 64 + lane], c3);
  out[(size_t)b * 64 + lane] = fmaxf(c3, 0.f);
}

extern "C" void kernel_launch(void* const* d_in, const int* in_sizes, int n_in,
                              void* d_out, int out_size, void* d_ws, size_t ws_size,
                              hipStream_t stream) {
  const int* uids = (const int*)d_in[0];
  const int* u_item_pad = (const int*)d_in[1];
  const int* u_user_pad = (const int*)d_in[2];
  const int* u_user_item_pad = (const int*)d_in[3];
  const float* user_table = (const float*)d_in[4];
  const float* item_table = (const float*)d_in[5];
  const float* rate_table = (const float*)d_in[6];
  const float* gv_W1 = (const float*)d_in[7];
  const float* gv_b1 = (const float*)d_in[8];
  const float* gv_W2 = (const float*)d_in[9];
  const float* gv_b2 = (const float*)d_in[10];
  const float* atti_W1 = (const float*)d_in[11];
  const float* atti_b1 = (const float*)d_in[12];
  const float* atti_W2 = (const float*)d_in[13];
  const float* atti_b2 = (const float*)d_in[14];
  const float* agg_W = (const float*)d_in[15];
  const float* agg_b = (const float*)d_in[16];
  const float* attu_W1 = (const float*)d_in[17];
  const float* attu_b1 = (const float*)d_in[18];
  const float* attu_W2 = (const float*)d_in[19];
  const float* attu_b2 = (const float*)d_in[20];
  const float* aggn_W = (const float*)d_in[21];
  const float* aggn_b = (const float*)d_in[22];
  const float* cm_W1 = (const float*)d_in[23];
  const float* cm_b1 = (const float*)d_in[24];
  const float* cm_W2 = (const float*)d_in[25];
  const float* cm_b2 = (const float*)d_in[26];
  const float* cm_W3 = (const float*)d_in[27];
  const float* cm_b3 = (const float*)d_in[28];
  float* out = (float*)d_out;

  float* hoI = (float*)d_ws;                 // 512*40*64 floats
  float* hiI = hoI + (size_t)512 * 40 * 64;  // 512*64 floats
  char* img = (char*)(hiI + (size_t)512 * 64);  // 28KB weight image

  // Block-invariant weight image (once, 5 tiny blocks).
  prep_kernel<<<5, 256, 0, stream>>>(rate_table, gv_W1, gv_b1, gv_W2, gv_b2,
                                     atti_W1, atti_b1, img);
  // Merged I (128 blocks x 4 groups, dispatched first) + S (1280 x 16).
  agg_kernel<<<128 + 1280, 256, 0, stream>>>(
      128, u_user_item_pad, u_user_pad, u_item_pad, uids,
      user_table, item_table, atti_W1,
      gv_b2, atti_W2, atti_b2,
      agg_W, agg_b, img, hoI, hiI);
  // Beta attention + h_iS + final MLP (wave-autonomous MFMA).
  stage2_kernel<<<256, 128, 0, stream>>>(u_user_pad, user_table, hoI, hiI,
                                         attu_W1, attu_b1, attu_W2, attu_b2,
                                         aggn_W, aggn_b,
                                         cm_W1, cm_b1, cm_W2, cm_b2, cm_W3, cm_b3,
                                         out);
}

// Round 15
// 241.072 us; speedup vs baseline: 1.1486x; 1.0039x over previous
//
#include <hip/hip_runtime.h>
#include <math.h>

#define EPSV 1e-10f

typedef _Float16 f16x8 __attribute__((ext_vector_type(8)));
typedef _Float16 f16x4 __attribute__((ext_vector_type(4)));
typedef float f32x4 __attribute__((ext_vector_type(4)));

// ---------------- agg LDS layout (bytes), R21 (32KB) ----------------
// A (0..8192):      W1T f16 [64][128] swz (copied from img) -> 4 wave-private
//                   H slots (wave*2048) in main loop; csW at flush.
// B (8192..16384):  W2T image (copied)
// C (16384..24576): M2T image (copied)
// D (24576..28672): cst (24576..24832) + sR1 (25856..27488) (copied)
// E (28672..32768): sV[g][n], g < 16 (copied from precomputed sVws)
// The 28KB weight image is byte-identical to LDS [0,28672); sV is now ALSO
// precomputed (prep_all) -> agg prologue = 8 float4 copies + hoist.
#define OFF_W1T  0
#define OFF_W2T  8192
#define OFF_M2T  16384
#define OFF_CST  24576
#define OFF_R1   25856
#define OFF_V    28672
#define SMEM_SZ  32768
#define IMG_SZ   28672
#define N_SGRP   20480   // 512*40 S-groups
#define N_GRP    20992   // + 512 I-groups

__device__ __forceinline__ f16x8 cvt_f16x8(const float4 a, const float4 b) {
  f16x8 h;
  h[0] = (_Float16)a.x; h[1] = (_Float16)a.y; h[2] = (_Float16)a.z; h[3] = (_Float16)a.w;
  h[4] = (_Float16)b.x; h[5] = (_Float16)b.y; h[6] = (_Float16)b.z; h[7] = (_Float16)b.w;
  return h;
}

// DPP quad_perm adds: exact xor-1 / xor-2 cross-lane sums at VALU speed.
__device__ __forceinline__ float qpx1_add(float x) {
  return x + __int_as_float(__builtin_amdgcn_update_dpp(
                 0, __float_as_int(x), 0xB1, 0xF, 0xF, false));
}
__device__ __forceinline__ float qpx2_add(float x) {
  return x + __int_as_float(__builtin_amdgcn_update_dpp(
                 0, __float_as_int(x), 0x4E, 0xF, 0xF, false));
}

// ---------------------------------------------------------------------------
// prep_all: one-time block-invariant work.
//  blocks 0..4:  weight image phases (W1T/W2T/M2T/sR1/cst) -> img[28KB]
//  blocks 5..332: sV precompute, 64 groups each (20992 = 328*64 exact):
//    sVws[j][n] = user_table[uid_j] . AW1u[:,n]  (f32, SAME float4 summation
//    order as the old in-agg P1 -> bit-identical results).
//    uid_j = u_user_pad[j] for j<20480 else uids[j-20480].
// ---------------------------------------------------------------------------
__global__ __launch_bounds__(256, 2) void prep_all(
    const float* __restrict__ rate_table,
    const float* __restrict__ gv_W1, const float* __restrict__ gv_b1,
    const float* __restrict__ gv_W2, const float* __restrict__ gv_b2,
    const float* __restrict__ atti_W1, const float* __restrict__ atti_b1,
    const int* __restrict__ u_user_pad, const int* __restrict__ uids,
    const float* __restrict__ user_table,
    char* __restrict__ img, float* __restrict__ sVws) {
  __shared__ __align__(16) char smem[SMEM_SZ];
  const int tid = threadIdx.x;
  const int wave = tid >> 6, lane = tid & 63;
  const int quad = lane >> 4, mrow = lane & 15;
  const int phase = (int)blockIdx.x;

  if (phase == 0) {  // W1T[n][k], k in 0..63 (item half of gv_W1)
    for (int o = tid; o < 1024; o += 256) {
      const int k = o >> 4, fb = o & 15;
      const float4 v = ((const float4*)(gv_W1 + k * 64))[fb];
      const float* vp = (const float*)&v;
#pragma unroll
      for (int c = 0; c < 4; ++c) {
        const int n = fb * 4 + c;
        *(_Float16*)(img + n * 128 + ((((k >> 3) ^ (n & 7))) << 4) +
                     ((k & 7) << 1)) = (_Float16)vp[c];
      }
    }
  } else if (phase == 1) {  // W2T[n2][h]
    for (int o = tid; o < 1024; o += 256) {
      const int h = o >> 4, fb = o & 15;
      const float4 v = ((const float4*)(gv_W2 + h * 64))[fb];
      const float* vp = (const float*)&v;
#pragma unroll
      for (int c = 0; c < 4; ++c) {
        const int n = fb * 4 + c;
        *(_Float16*)(img + 8192 + n * 128 + ((((h >> 3) ^ (n & 7))) << 4) +
                     ((h & 7) << 1)) = (_Float16)vp[c];
      }
    }
  } else if (phase == 2) {  // M2T = W2 . AW1x via MFMA (4 waves cover n3)
    f16x8 aM[2];
#pragma unroll
    for (int ks = 0; ks < 2; ++ks) {
      f16x8 t;
#pragma unroll
      for (int j = 0; j < 8; ++j)
        t[j] = (_Float16)atti_W1[(ks * 32 + quad * 8 + j) * 64 + (wave * 16 + mrow)];
      aM[ks] = t;
    }
#pragma unroll
    for (int ht = 0; ht < 4; ++ht) {
      f32x4 c = {0.f, 0.f, 0.f, 0.f};
#pragma unroll
      for (int ks = 0; ks < 2; ++ks) {
        const float* s = gv_W2 + (ht * 16 + mrow) * 64 + ks * 32 + quad * 8;
        f16x8 b;
#pragma unroll
        for (int j = 0; j < 8; ++j) b[j] = (_Float16)s[j];
        c = __builtin_amdgcn_mfma_f32_16x16x32_f16(aM[ks], b, c, 0, 0, 0);
      }
      const int h = ht * 16 + mrow;
#pragma unroll
      for (int rg = 0; rg < 4; ++rg) {
        const int n3 = wave * 16 + quad * 4 + rg;
        *(_Float16*)(img + 16384 + n3 * 128 + ((((h >> 3) ^ (n3 & 7))) << 4) +
                     ((h & 7) << 1)) = (_Float16)c[rg];
      }
    }
  } else if (phase == 3) {  // sR1[r][n] = rate_r . W1[64:,n] + b1[n]
    float* sR1 = (float*)(img + OFF_R1);
    for (int o = tid; o < 384; o += 256) {
      const int r = o >> 6, n = o & 63;
      float s = gv_b1[n];
#pragma unroll 8
      for (int k = 0; k < 64; ++k)
        s = fmaf(rate_table[r * 64 + k], gv_W1[(64 + k) * 64 + n], s);
      sR1[r * 68 + n] = s;
    }
  } else if (phase == 4) {  // cst[n] = atti_b1[n] + gv_b2 . atti_W1[:,n]
    if (tid < 64) {
      float p = atti_b1[tid];
#pragma unroll 8
      for (int j = 0; j < 64; ++j) p = fmaf(gv_b2[j], atti_W1[j * 64 + tid], p);
      ((float*)(img + OFF_CST))[tid] = p;
    }
  } else {  // sV precompute: 64 groups per block
    const int sb = phase - 5;
    const int jbase = sb * 64;
    float* AU = (float*)smem;              // 16KB f4-swizzled
    float* uS = (float*)(smem + 16384);    // 16KB, 64 group rows
    for (int o = tid; o < 1024; o += 256) {  // AU[j][k] = atti_W1[64+k][j]
      const int k = o >> 4, fb = o & 15;
      const float4 v = ((const float4*)(atti_W1 + (64 + k) * 64))[fb];
      const float* vp = (const float*)&v;
#pragma unroll
      for (int c = 0; c < 4; ++c) {
        const int j = fb * 4 + c;
        AU[j * 64 + (((k >> 2) ^ (j & 15)) << 2) + (k & 3)] = vp[c];
      }
    }
    for (int t = tid; t < 4096; t += 256) {
      const int g = t >> 6, f = t & 63;
      const int j = jbase + g;
      const int uid = j < N_SGRP ? u_user_pad[j] : uids[j - N_SGRP];
      uS[t] = user_table[(size_t)uid * 64 + f];
    }
    __syncthreads();
    const float4* u4 = (const float4*)uS;
    const float4* a4 = (const float4*)AU;
    for (int t = tid; t < 4096; t += 256) {
      const int g = t >> 6, jn = t & 63;
      float s = 0.f;
#pragma unroll 4
      for (int kb = 0; kb < 16; ++kb) {
        const float4 uu = u4[g * 16 + kb];
        const float4 aa = a4[jn * 16 + (kb ^ (jn & 15))];
        s += uu.x * aa.x + uu.y * aa.y + uu.z * aa.z + uu.w * aa.w;
      }
      sVws[(size_t)(jbase + g) * 64 + jn] = s;
    }
  }
}

// ---------------------------------------------------------------------------
// Fused item-aggregation. I-blocks FIRST [0,nIblk): 4 groups (P=100, 1/wave);
// S-blocks after: 16 groups (P=40, 4/wave). 256 thr = 4 waves.
// R21: complete the prologue amortization (R20 WIN: 123->93us). sV is now
// also precomputed (prep_all) -> agg's P0/P1 (uS gather, 16KB AU scatter
// repeated 1408x, per-thread 64 ds_read_b128 dots, 2 barriers) collapse to
// ONE float4 copy. Prologue = gather-issue + 8 float4 copies + hoist + 2
// barriers. Main loop = R18 verbatim (best known).
// Tripwires: FETCH ~100-107MB / WRITE ~10.6MB (sVws legit) / VGPR ~76 /
// conflicts ~2.8M / absmax unchanged (bit-identical sV math).
// ---------------------------------------------------------------------------
__global__ __launch_bounds__(256, 3) void agg_kernel(
    const int nIblk,
    const int* __restrict__ idsS, const int* __restrict__ idsI,
    const float* __restrict__ item_table,
    const float* __restrict__ gv_b2, const float* __restrict__ atti_W2,
    const float* __restrict__ atti_b2,
    const float* __restrict__ agg_W, const float* __restrict__ agg_b,
    const char* __restrict__ img, const float* __restrict__ sVws,
    float* __restrict__ outS, float* __restrict__ outI) {
  __shared__ __align__(16) char smem[SMEM_SZ];
  const int tid = threadIdx.x;
  const int wave = tid >> 6, lane = tid & 63;
  const int quad = lane >> 4, mrow = lane & 15;

  const bool isS = (int)blockIdx.x >= nIblk;
  const int NG = isS ? 16 : 4;
  const int P = isS ? 40 : 100;
  const int nGrp = isS ? 4 : 1;  // groups per wave
  const int tpg = isS ? 3 : 8;   // 16-row tiles per group
  const int nIdx = nGrp * tpg;   // 12 or 8
  const int* __restrict__ ids = isS ? idsS : idsI;
  float* __restrict__ out = isS ? outS : outI;
  const int gbase = isS ? ((int)blockIdx.x - nIblk) * 16 : (int)blockIdx.x * 4;
  const int svbase = isS ? gbase : (N_SGRP + gbase);  // flat group index

  float* sV = (float*)(smem + OFF_V);
  char* smXw = smem + OFF_W1T + wave * 2048;  // wave-private H slot (post-B4)
  float* csW = (float*)smXw;                  // epilogue c vector (H dead then)

  // ---- gather prefetch pipeline (issued FIRST; hides under prologue) ----
  const int nIdxM1 = nIdx - 1;
  int2 idreg;
  float4 pf[4];
  float pm;
  int rid;
  auto load_ids = [&](int idx) __attribute__((always_inline)) {
    const int ic = idx < nIdxM1 ? idx : nIdxM1;  // clamp (tail prefetch harmless)
    const int gq = isS ? (ic * 11) >> 5 : (ic >> 3);  // /3 or /8, ic<=11
    const int tt = ic - gq * tpg;
    const int it = tt * 16 + mrow;
    int2 pr = make_int2(0, 0);
    if (it < P) {
      const int g2 = gbase + wave + 4 * gq;
      pr = ((const int2*)ids)[(size_t)g2 * P + it];
    }
    idreg = pr;
  };
  auto issue_gather = [&]() __attribute__((always_inline)) {
    const int iid = idreg.x;
    rid = idreg.y;
    pm = iid > 0 ? 1.f : 0.f;
    const float* ib = item_table + (size_t)iid * 64 + quad * 8;
    pf[0] = ((const float4*)ib)[0];
    pf[1] = ((const float4*)ib)[1];
    pf[2] = ((const float4*)(ib + 32))[0];
    pf[3] = ((const float4*)(ib + 32))[1];
  };
  load_ids(0); issue_gather();
  load_ids(1);

  // ---- prologue: 8 coalesced float4 copies (img 28KB + sV 4KB/1KB) ----
  {
    const float4* src = (const float4*)img;
    float4* dst = (float4*)smem;
#pragma unroll
    for (int o = 0; o < 7; ++o) dst[tid + o * 256] = src[tid + o * 256];
    if (tid < NG * 16)
      ((float4*)sV)[tid] = ((const float4*)(sVws + (size_t)svbase * 64))[tid];
  }
  // per-lane constant preloads (global, L2-hot)
  float b2v[4], aw2v[4];
#pragma unroll
  for (int nt = 0; nt < 4; ++nt) {
    b2v[nt] = gv_b2[nt * 16 + mrow];
    aw2v[nt] = atti_W2[nt * 16 + mrow];
  }
  const float ab2 = atti_b2[0];
  __syncthreads();  // B3: images + sV ready

  // ---- hoist W1 A-frags + cstv from the copied image ----
  f16x8 aW[4][2];
#pragma unroll
  for (int nt = 0; nt < 4; ++nt) {
#pragma unroll
    for (int ks = 0; ks < 2; ++ks)
      aW[nt][ks] = *(const f16x8*)(smem + OFF_W1T + (nt * 16 + mrow) * 128 +
                                   (((ks * 4 + quad) ^ (mrow & 7)) << 4));
  }
  float cstv[4];
  {
    const float* cst = (const float*)(smem + OFF_CST);
#pragma unroll
    for (int nt = 0; nt < 4; ++nt) cstv[nt] = cst[nt * 16 + mrow];
  }
  __syncthreads();  // B4: hoist done; region A becomes per-wave H slots

  // =================== barrier-free main loop (R18 verbatim) ===================
  const float* sR1 = (const float*)(smem + OFF_R1);
  float vv[4], pnum[4], pden = 0.f;
  for (int idx = 0; idx < nIdx; ++idx) {
    const int gq = isS ? (idx * 11) >> 5 : (idx >> 3);
    const int tt = idx - gq * tpg;
    const int g = wave + 4 * gq;
    if (tt == 0) {
#pragma unroll
      for (int nt = 0; nt < 4; ++nt) {
        vv[nt] = sV[g * 64 + nt * 16 + mrow];
        pnum[nt] = 0.f;
      }
      pden = 0.f;
    }
    // In B-frags straight from prefetched registers (no LDS)
    f16x8 bIn0 = cvt_f16x8(pf[0], pf[1]);
    f16x8 bIn1 = cvt_f16x8(pf[2], pf[3]);
    const unsigned long long mball = __ballot(pm > 0.5f);
    const int ridcur = rid;
    issue_gather();      // gather for tile idx+1 (ids in idreg)
    load_ids(idx + 2);   // ids for tile idx+2 -> idreg
    // ---- layer1 (transposed): H^T -> b64 writes to wave-private slot ----
#pragma unroll
    for (int nt = 0; nt < 4; ++nt) {
      f32x4 c = {0.f, 0.f, 0.f, 0.f};
      c = __builtin_amdgcn_mfma_f32_16x16x32_f16(aW[nt][0], bIn0, c, 0, 0, 0);
      c = __builtin_amdgcn_mfma_f32_16x16x32_f16(aW[nt][1], bIn1, c, 0, 0, 0);
      const float4 r1q = *(const float4*)(sR1 + ridcur * 68 + nt * 16 + quad * 4);
      const float* r1p = (const float*)&r1q;
      f16x4 hv;
#pragma unroll
      for (int rg = 0; rg < 4; ++rg)
        hv[rg] = (_Float16)fmaxf(c[rg] + r1p[rg], 0.f);
      *(f16x4*)(smXw + mrow * 128 +
                (((nt * 2 + (quad >> 1)) ^ (mrow & 7)) << 4) +
                ((quad & 1) << 3)) = hv;
    }
    // ---- H A-frags for layer2 + attention ----
    f16x8 a2[2];
#pragma unroll
    for (int ks = 0; ks < 2; ++ks)
      a2[ks] = *(const f16x8*)(smXw + mrow * 128 +
                               (((ks * 4 + quad) ^ (mrow & 7)) << 4));
    float mk[4];
#pragma unroll
    for (int rg = 0; rg < 4; ++rg)
      mk[rg] = (float)((mball >> (quad * 4 + rg)) & 1ULL);
    // d-path first (attention logits); c-path MFMAs are e-independent
    float tl[4] = {0.f, 0.f, 0.f, 0.f};
#pragma unroll
    for (int nt = 0; nt < 4; ++nt) {
      f32x4 d = {0.f, 0.f, 0.f, 0.f};
#pragma unroll
      for (int ks = 0; ks < 2; ++ks) {
        const f16x8 bM = *(const f16x8*)(smem + OFF_M2T + (nt * 16 + mrow) * 128 +
                                         (((ks * 4 + quad) ^ (mrow & 7)) << 4));
        d = __builtin_amdgcn_mfma_f32_16x16x32_f16(a2[ks], bM, d, 0, 0, 0);
      }
#pragma unroll
      for (int rg = 0; rg < 4; ++rg) {
        const float hh = fmaxf(d[rg] + cstv[nt] + mk[rg] * vv[nt], 0.f);
        tl[rg] = fmaf(hh, aw2v[nt], tl[rg]);
      }
    }
    float e[4];
#pragma unroll
    for (int rg = 0; rg < 4; ++rg) {
      float t = tl[rg];
      t = qpx1_add(t);          // xor-1 via DPP quad_perm (VALU)
      t = qpx2_add(t);          // xor-2 via DPP quad_perm (VALU)
      t += __shfl_xor(t, 4); t += __shfl_xor(t, 8);
      e[rg] = __expf(t + ab2) * mk[rg];
      pden += e[rg];
    }
    // c-path (x2) consumed straight into pnum (b2 folded at flush)
#pragma unroll
    for (int nt = 0; nt < 4; ++nt) {
      f32x4 c = {0.f, 0.f, 0.f, 0.f};
#pragma unroll
      for (int ks = 0; ks < 2; ++ks) {
        const f16x8 bW = *(const f16x8*)(smem + OFF_W2T + (nt * 16 + mrow) * 128 +
                                         (((ks * 4 + quad) ^ (mrow & 7)) << 4));
        c = __builtin_amdgcn_mfma_f32_16x16x32_f16(a2[ks], bW, c, 0, 0, 0);
      }
      pnum[nt] = fmaf(e[0], c[0], pnum[nt]);
      pnum[nt] = fmaf(e[1], c[1], pnum[nt]);
      pnum[nt] = fmaf(e[2], c[2], pnum[nt]);
      pnum[nt] = fmaf(e[3], c[3], pnum[nt]);
    }
    if (tt == tpg - 1) {
      // ---- group flush (wave-local): quad-reduce + agg matvec + store ----
      float dsum = pden;
      dsum += __shfl_xor(dsum, 16); dsum += __shfl_xor(dsum, 32);
      const float rd = 1.f / (dsum + EPSV);
#pragma unroll
      for (int nt = 0; nt < 4; ++nt) {
        float s = pnum[nt];
        s += __shfl_xor(s, 16); s += __shfl_xor(s, 32);
        if (quad == 0) csW[nt * 16 + mrow] = (s + b2v[nt] * dsum) * rd;
      }
      float acc = agg_b[lane];
#pragma unroll 8
      for (int k = 0; k < 64; ++k) acc = fmaf(csW[k], agg_W[k * 64 + lane], acc);
      out[(size_t)(gbase + g) * 64 + lane] = fmaxf(acc, 0.f);
    }
  }
}

// ---------------- stage2 LDS layout (bytes) ----------------
#define S2_W1T 0       // 17408: attu_W1^T f16 [n][k], pitch 272 (bank-rotated)
#define S2_X   17408   // 8704:  2 waves x 16 rows x 272B
#define S2_E   26112   // 128:   2 x 16 f32
#define S2_MSK 26240   // 128:   2 x 16 f32
#define S2_HB  26368   // 1536:  2 x 192 f32 (concat/hidden ping-pong)
#define S2_SZ  27904

// ---------------------------------------------------------------------------
// Kernel 2: beta attention (MFMA) + h_iS + final 3-layer MLP.
// 256 blocks x 128 thr; wave w handles b = blockIdx*2 + w autonomously.
// ---------------------------------------------------------------------------
__global__ __launch_bounds__(128, 2) void stage2_kernel(
    const int* __restrict__ u_user_pad, const float* __restrict__ user_table,
    const float* __restrict__ hoI, const float* __restrict__ hiI,
    const float* __restrict__ attu_W1, const float* __restrict__ attu_b1,
    const float* __restrict__ attu_W2, const float* __restrict__ attu_b2,
    const float* __restrict__ aggn_W, const float* __restrict__ aggn_b,
    const float* __restrict__ cm_W1, const float* __restrict__ cm_b1,
    const float* __restrict__ cm_W2, const float* __restrict__ cm_b2,
    const float* __restrict__ cm_W3, const float* __restrict__ cm_b3,
    float* __restrict__ out) {
  __shared__ __align__(16) char smem[S2_SZ];
  const int tid = threadIdx.x;
  const int wave = tid >> 6, lane = tid & 63;
  const int quad = lane >> 4, mrow = lane & 15;
  const int b = (int)blockIdx.x * 2 + wave;

  char* sW1 = smem + S2_W1T;
  char* sXw = smem + S2_X + wave * 4352;
  float* sE = (float*)(smem + S2_E) + wave * 16;
  float* sM = (float*)(smem + S2_MSK) + wave * 16;
  float* sB = (float*)(smem + S2_HB) + wave * 192;

  for (int o = tid; o < 2048; o += 128) {
    const int k = o >> 4, fb = o & 15;
    const float4 v = ((const float4*)(attu_W1 + k * 64))[fb];
    const float* vp = (const float*)&v;
#pragma unroll
    for (int c = 0; c < 4; ++c) {
      const int n = fb * 4 + c;
      *(_Float16*)(sW1 + n * 272 + ((k >> 3) << 4) + ((k & 7) << 1)) = (_Float16)vp[c];
    }
  }
  float b1v[4], w2v[4];
#pragma unroll
  for (int nt = 0; nt < 4; ++nt) {
    b1v[nt] = attu_b1[nt * 16 + mrow];
    w2v[nt] = attu_W2[nt * 16 + mrow];
  }
  const float b2s = attu_b2[0];

  float4 pa[4], pb[4];
  float msk[4];
  auto pf = [&](int tt) __attribute__((always_inline)) {
#pragma unroll
    for (int k = 0; k < 4; ++k) {
      const int u = lane + (k << 6);
      const int r = u >> 4, bb = u & 15;
      const int q = tt * 16 + r;
      const int qc = q < 40 ? q : 39;
      int uid = 0;
      float m = 0.f;
      if (q < 40) {
        uid = u_user_pad[b * 40 + q];
        m = uid > 0 ? 1.f : 0.f;
      }
      msk[k] = m;
      const float* src = (bb < 8)
                             ? hoI + ((size_t)b * 40 + qc) * 64 + bb * 8
                             : user_table + (size_t)uid * 64 + (bb - 8) * 8;
      pa[k] = ((const float4*)src)[0];
      pb[k] = ((const float4*)src)[1];
    }
  };
  pf(0);
  __syncthreads();  // W1T ready

  float numer = 0.f, pden = 0.f;
  for (int tt = 0; tt < 3; ++tt) {
#pragma unroll
    for (int k = 0; k < 4; ++k) {
      const int u = lane + (k << 6);
      const int r = u >> 4, bb = u & 15;
      *(f16x8*)(sXw + r * 272 + (bb << 4)) = cvt_f16x8(pa[k], pb[k]);
      if (bb == 0) sM[r] = msk[k];
    }
    if (tt < 2) pf(tt + 1);
    f16x8 a[4];
#pragma unroll
    for (int ks = 0; ks < 4; ++ks)
      a[ks] = *(const f16x8*)(sXw + mrow * 272 + ((ks * 4 + quad) << 4));
    float mk[4];
#pragma unroll
    for (int rg = 0; rg < 4; ++rg) mk[rg] = sM[quad * 4 + rg];
    float tl[4] = {0.f, 0.f, 0.f, 0.f};
#pragma unroll
    for (int nt = 0; nt < 4; ++nt) {
      f32x4 d = {0.f, 0.f, 0.f, 0.f};
      const int n = nt * 16 + mrow;
#pragma unroll
      for (int ks = 0; ks < 4; ++ks) {
        const f16x8 bW = *(const f16x8*)(sW1 + n * 272 + ((ks * 4 + quad) << 4));
        d = __builtin_amdgcn_mfma_f32_16x16x32_f16(a[ks], bW, d, 0, 0, 0);
      }
#pragma unroll
      for (int rg = 0; rg < 4; ++rg) {
        const float h = fmaxf(d[rg] + b1v[nt], 0.f);
        tl[rg] = fmaf(h, w2v[nt], tl[rg]);
      }
    }
    float e[4];
#pragma unroll
    for (int rg = 0; rg < 4; ++rg) {
      float t = tl[rg];
      t = qpx1_add(t);
      t = qpx2_add(t);
      t += __shfl_xor(t, 4); t += __shfl_xor(t, 8);
      e[rg] = __expf(t + b2s) * mk[rg];
      pden += e[rg];
    }
    if (mrow == 0) {
#pragma unroll
      for (int rg = 0; rg < 4; ++rg) sE[quad * 4 + rg] = e[rg];
    }
#pragma unroll 4
    for (int r = 0; r < 16; ++r) {
      const float er = sE[r];
      const float xv = (float)*(const _Float16*)(sXw + r * 272 + ((lane >> 3) << 4) +
                                                 ((lane & 7) << 1));
      numer = fmaf(er, xv, numer);
    }
  }
  pden += __shfl_xor(pden, 16);
  pden += __shfl_xor(pden, 32);
  const float hagg = numer / (pden + EPSV);

  sB[128 + lane] = hagg;
  sB[lane] = hiI[(size_t)b * 64 + lane];
  float acc = aggn_b[lane];
#pragma unroll 8
  for (int k = 0; k < 64; ++k) acc = fmaf(sB[128 + k], aggn_W[k * 64 + lane], acc);
  sB[64 + lane] = fmaxf(acc, 0.f);
  float c1 = cm_b1[lane];
#pragma unroll 8
  for (int k = 0; k < 128; ++k) c1 = fmaf(sB[k], cm_W1[k * 64 + lane], c1);
  sB[128 + lane] = fmaxf(c1, 0.f);
  float c2 = cm_b2[lane];
#pragma unroll 8
  for (int k = 0; k < 64; ++k) c2 = fmaf(sB[128 + k], cm_W2[k * 64 + lane], c2);
  sB[lane] = fmaxf(c2, 0.f);
  float c3 = cm_b3[lane];
#pragma unroll 8
  for (int k = 0; k < 64; ++k) c3 = fmaf(sB[k], cm_W3[k * 64 + lane], c3);
  out[(size_t)b * 64 + lane] = fmaxf(c3, 0.f);
}

extern "C" void kernel_launch(void* const* d_in, const int* in_sizes, int n_in,
                              void* d_out, int out_size, void* d_ws, size_t ws_size,
                              hipStream_t stream) {
  const int* uids = (const int*)d_in[0];
  const int* u_item_pad = (const int*)d_in[1];
  const int* u_user_pad = (const int*)d_in[2];
  const int* u_user_item_pad = (const int*)d_in[3];
  const float* user_table = (const float*)d_in[4];
  const float* item_table = (const float*)d_in[5];
  const float* rate_table = (const float*)d_in[6];
  const float* gv_W1 = (const float*)d_in[7];
  const float* gv_b1 = (const float*)d_in[8];
  const float* gv_W2 = (const float*)d_in[9];
  const float* gv_b2 = (const float*)d_in[10];
  const float* atti_W1 = (const float*)d_in[11];
  const float* atti_b1 = (const float*)d_in[12];
  const float* atti_W2 = (const float*)d_in[13];
  const float* atti_b2 = (const float*)d_in[14];
  const float* agg_W = (const float*)d_in[15];
  const float* agg_b = (const float*)d_in[16];
  const float* attu_W1 = (const float*)d_in[17];
  const float* attu_b1 = (const float*)d_in[18];
  const float* attu_W2 = (const float*)d_in[19];
  const float* attu_b2 = (const float*)d_in[20];
  const float* aggn_W = (const float*)d_in[21];
  const float* aggn_b = (const float*)d_in[22];
  const float* cm_W1 = (const float*)d_in[23];
  const float* cm_b1 = (const float*)d_in[24];
  const float* cm_W2 = (const float*)d_in[25];
  const float* cm_b2 = (const float*)d_in[26];
  const float* cm_W3 = (const float*)d_in[27];
  const float* cm_b3 = (const float*)d_in[28];
  float* out = (float*)d_out;

  float* hoI = (float*)d_ws;                    // 512*40*64 floats
  float* hiI = hoI + (size_t)512 * 40 * 64;     // 512*64 floats
  char* img = (char*)(hiI + (size_t)512 * 64);  // 28KB weight image
  float* sVws = (float*)(img + IMG_SZ);         // 20992*64 floats (~5.4MB)

  // One-time block-invariant work: weight image (5 blocks) + sV (328 blocks).
  prep_all<<<5 + 328, 256, 0, stream>>>(rate_table, gv_W1, gv_b1, gv_W2,
                                        gv_b2, atti_W1, atti_b1,
                                        u_user_pad, uids, user_table,
                                        img, sVws);
  // Merged I (128 blocks x 4 groups, dispatched first) + S (1280 x 16).
  agg_kernel<<<128 + 1280, 256, 0, stream>>>(
      128, u_user_item_pad, u_item_pad, item_table,
      gv_b2, atti_W2, atti_b2, agg_W, agg_b, img, sVws, hoI, hiI);
  // Beta attention + h_iS + final MLP (wave-autonomous MFMA).
  stage2_kernel<<<256, 128, 0, stream>>>(u_user_pad, user_table, hoI, hiI,
                                         attu_W1, attu_b1, attu_W2, attu_b2,
                                         aggn_W, aggn_b,
                                         cm_W1, cm_b1, cm_W2, cm_b2, cm_W3, cm_b3,
                                         out);
}

// Round 16
// 241.041 us; speedup vs baseline: 1.1487x; 1.0001x over previous
//
#include <hip/hip_runtime.h>
#include <math.h>

#define EPSV 1e-10f

typedef _Float16 f16x8 __attribute__((ext_vector_type(8)));
typedef _Float16 f16x4 __attribute__((ext_vector_type(4)));
typedef float f32x4 __attribute__((ext_vector_type(4)));

// ---------------- agg LDS layout (bytes), R22 (32KB) ----------------
// A (0..8192):      W1T f16 [64][128] swz (copied from img) -> 4 wave-private
//                   H slots (wave*2048) in main loop; csW at flush.
// B (8192..16384):  W2T image (copied)
// C (16384..24576): M2T image (copied)
// D (24576..28672): cst (24576..24832) + sR1 (25856..27488) (copied)
// E (28672..32768): sV[g][n], g < 16 (copied from precomputed sVws)
#define OFF_W1T  0
#define OFF_W2T  8192
#define OFF_M2T  16384
#define OFF_CST  24576
#define OFF_R1   25856
#define OFF_V    28672
#define SMEM_SZ  32768
#define IMG_SZ   28672
#define N_SGRP   20480   // 512*40 S-groups
#define N_GRP    20992   // + 512 I-groups

__device__ __forceinline__ f16x8 cvt_f16x8(const float4 a, const float4 b) {
  f16x8 h;
  h[0] = (_Float16)a.x; h[1] = (_Float16)a.y; h[2] = (_Float16)a.z; h[3] = (_Float16)a.w;
  h[4] = (_Float16)b.x; h[5] = (_Float16)b.y; h[6] = (_Float16)b.z; h[7] = (_Float16)b.w;
  return h;
}

// DPP quad_perm adds: exact xor-1 / xor-2 cross-lane sums at VALU speed.
__device__ __forceinline__ float qpx1_add(float x) {
  return x + __int_as_float(__builtin_amdgcn_update_dpp(
                 0, __float_as_int(x), 0xB1, 0xF, 0xF, false));
}
__device__ __forceinline__ float qpx2_add(float x) {
  return x + __int_as_float(__builtin_amdgcn_update_dpp(
                 0, __float_as_int(x), 0x4E, 0xF, 0xF, false));
}

// ---------------------------------------------------------------------------
// prep_all: one-time block-invariant work.
//  blocks 0..4:      weight image phases (W1T/W2T/M2T/sR1/cst) -> img[28KB]
//  blocks 5..1316:   sV precompute, 16 groups each (20992 = 1312*16 exact).
//    R22: was 328x64-group blocks (1.3 blocks/CU -> ~13us serial, machine
//    idle); 1312x16 gives 4x parallelism at identical math/summation order
//    (bit-identical sV).
// ---------------------------------------------------------------------------
__global__ __launch_bounds__(256, 2) void prep_all(
    const float* __restrict__ rate_table,
    const float* __restrict__ gv_W1, const float* __restrict__ gv_b1,
    const float* __restrict__ gv_W2, const float* __restrict__ gv_b2,
    const float* __restrict__ atti_W1, const float* __restrict__ atti_b1,
    const int* __restrict__ u_user_pad, const int* __restrict__ uids,
    const float* __restrict__ user_table,
    char* __restrict__ img, float* __restrict__ sVws) {
  __shared__ __align__(16) char smem[SMEM_SZ];
  const int tid = threadIdx.x;
  const int wave = tid >> 6, lane = tid & 63;
  const int quad = lane >> 4, mrow = lane & 15;
  const int phase = (int)blockIdx.x;

  if (phase == 0) {  // W1T[n][k], k in 0..63 (item half of gv_W1)
    for (int o = tid; o < 1024; o += 256) {
      const int k = o >> 4, fb = o & 15;
      const float4 v = ((const float4*)(gv_W1 + k * 64))[fb];
      const float* vp = (const float*)&v;
#pragma unroll
      for (int c = 0; c < 4; ++c) {
        const int n = fb * 4 + c;
        *(_Float16*)(img + n * 128 + ((((k >> 3) ^ (n & 7))) << 4) +
                     ((k & 7) << 1)) = (_Float16)vp[c];
      }
    }
  } else if (phase == 1) {  // W2T[n2][h]
    for (int o = tid; o < 1024; o += 256) {
      const int h = o >> 4, fb = o & 15;
      const float4 v = ((const float4*)(gv_W2 + h * 64))[fb];
      const float* vp = (const float*)&v;
#pragma unroll
      for (int c = 0; c < 4; ++c) {
        const int n = fb * 4 + c;
        *(_Float16*)(img + 8192 + n * 128 + ((((h >> 3) ^ (n & 7))) << 4) +
                     ((h & 7) << 1)) = (_Float16)vp[c];
      }
    }
  } else if (phase == 2) {  // M2T = W2 . AW1x via MFMA (4 waves cover n3)
    f16x8 aM[2];
#pragma unroll
    for (int ks = 0; ks < 2; ++ks) {
      f16x8 t;
#pragma unroll
      for (int j = 0; j < 8; ++j)
        t[j] = (_Float16)atti_W1[(ks * 32 + quad * 8 + j) * 64 + (wave * 16 + mrow)];
      aM[ks] = t;
    }
#pragma unroll
    for (int ht = 0; ht < 4; ++ht) {
      f32x4 c = {0.f, 0.f, 0.f, 0.f};
#pragma unroll
      for (int ks = 0; ks < 2; ++ks) {
        const float* s = gv_W2 + (ht * 16 + mrow) * 64 + ks * 32 + quad * 8;
        f16x8 b;
#pragma unroll
        for (int j = 0; j < 8; ++j) b[j] = (_Float16)s[j];
        c = __builtin_amdgcn_mfma_f32_16x16x32_f16(aM[ks], b, c, 0, 0, 0);
      }
      const int h = ht * 16 + mrow;
#pragma unroll
      for (int rg = 0; rg < 4; ++rg) {
        const int n3 = wave * 16 + quad * 4 + rg;
        *(_Float16*)(img + 16384 + n3 * 128 + ((((h >> 3) ^ (n3 & 7))) << 4) +
                     ((h & 7) << 1)) = (_Float16)c[rg];
      }
    }
  } else if (phase == 3) {  // sR1[r][n] = rate_r . W1[64:,n] + b1[n]
    float* sR1 = (float*)(img + OFF_R1);
    for (int o = tid; o < 384; o += 256) {
      const int r = o >> 6, n = o & 63;
      float s = gv_b1[n];
#pragma unroll 8
      for (int k = 0; k < 64; ++k)
        s = fmaf(rate_table[r * 64 + k], gv_W1[(64 + k) * 64 + n], s);
      sR1[r * 68 + n] = s;
    }
  } else if (phase == 4) {  // cst[n] = atti_b1[n] + gv_b2 . atti_W1[:,n]
    if (tid < 64) {
      float p = atti_b1[tid];
#pragma unroll 8
      for (int j = 0; j < 64; ++j) p = fmaf(gv_b2[j], atti_W1[j * 64 + tid], p);
      ((float*)(img + OFF_CST))[tid] = p;
    }
  } else {  // sV precompute: 16 groups per block (4x parallelism vs R21)
    const int sb = phase - 5;
    const int jbase = sb * 16;
    float* AU = (float*)smem;              // 16KB f4-swizzled
    float* uS = (float*)(smem + 16384);    // 4KB, 16 group rows
    for (int o = tid; o < 1024; o += 256) {  // AU[j][k] = atti_W1[64+k][j]
      const int k = o >> 4, fb = o & 15;
      const float4 v = ((const float4*)(atti_W1 + (64 + k) * 64))[fb];
      const float* vp = (const float*)&v;
#pragma unroll
      for (int c = 0; c < 4; ++c) {
        const int j = fb * 4 + c;
        AU[j * 64 + (((k >> 2) ^ (j & 15)) << 2) + (k & 3)] = vp[c];
      }
    }
    for (int t = tid; t < 1024; t += 256) {
      const int g = t >> 6, f = t & 63;
      const int j = jbase + g;
      const int uid = j < N_SGRP ? u_user_pad[j] : uids[j - N_SGRP];
      uS[t] = user_table[(size_t)uid * 64 + f];
    }
    __syncthreads();
    const float4* u4 = (const float4*)uS;
    const float4* a4 = (const float4*)AU;
    for (int t = tid; t < 1024; t += 256) {
      const int g = t >> 6, jn = t & 63;
      float s = 0.f;
#pragma unroll 4
      for (int kb = 0; kb < 16; ++kb) {
        const float4 uu = u4[g * 16 + kb];
        const float4 aa = a4[jn * 16 + (kb ^ (jn & 15))];
        s += uu.x * aa.x + uu.y * aa.y + uu.z * aa.z + uu.w * aa.w;
      }
      sVws[(size_t)(jbase + g) * 64 + jn] = s;
    }
  }
}

// ---------------------------------------------------------------------------
// Fused item-aggregation. I-blocks FIRST [0,nIblk): 4 groups (P=100, 1/wave);
// S-blocks after: 16 groups (P=40, 4/wave). 256 thr = 4 waves.
// R22: 2-deep gather prefetch (R9b's proven pfA/pfB parity structure) on the
// R21 body. Wave lifetime is now ~2.45us/tile (~5900cy) vs ~1100cy of issue
// work -> main loop is gather-latency-bound with 1-tile lookahead. The R9
// null on this lever is unconfounded now (prologue amortized away in R20/21).
// Invariant: idreg = ids(t+1) when tile t's body runs; body issues
// gather(t+1) into its own parity buffer then load_ids(t+2... via +3 calls).
// Tripwires: FETCH ~100MB / WRITE ~5.2MB / VGPR 90-100 / conflicts ~2.0M.
// ---------------------------------------------------------------------------
__global__ __launch_bounds__(256, 3) void agg_kernel(
    const int nIblk,
    const int* __restrict__ idsS, const int* __restrict__ idsI,
    const float* __restrict__ item_table,
    const float* __restrict__ gv_b2, const float* __restrict__ atti_W2,
    const float* __restrict__ atti_b2,
    const float* __restrict__ agg_W, const float* __restrict__ agg_b,
    const char* __restrict__ img, const float* __restrict__ sVws,
    float* __restrict__ outS, float* __restrict__ outI) {
  __shared__ __align__(16) char smem[SMEM_SZ];
  const int tid = threadIdx.x;
  const int wave = tid >> 6, lane = tid & 63;
  const int quad = lane >> 4, mrow = lane & 15;

  const bool isS = (int)blockIdx.x >= nIblk;
  const int NG = isS ? 16 : 4;
  const int P = isS ? 40 : 100;
  const int nGrp = isS ? 4 : 1;  // groups per wave
  const int tpg = isS ? 3 : 8;   // 16-row tiles per group
  const int nIdx = nGrp * tpg;   // 12 or 8 (both even)
  const int* __restrict__ ids = isS ? idsS : idsI;
  float* __restrict__ out = isS ? outS : outI;
  const int gbase = isS ? ((int)blockIdx.x - nIblk) * 16 : (int)blockIdx.x * 4;
  const int svbase = isS ? gbase : (N_SGRP + gbase);  // flat group index

  float* sV = (float*)(smem + OFF_V);
  char* smXw = smem + OFF_W1T + wave * 2048;  // wave-private H slot (post-B4)
  float* csW = (float*)smXw;                  // epilogue c vector (H dead then)

  // ---- 2-deep gather prefetch pipeline (R9b parity structure) ----
  const int nIdxM1 = nIdx - 1;
  int2 idreg;
  float4 pfA[4], pfB[4];
  float pmA, pmB;
  int ridA, ridB;
  auto load_ids = [&](int idx) __attribute__((always_inline)) {
    const int ic = idx < nIdxM1 ? idx : nIdxM1;  // clamp (tail prefetch harmless)
    const int gq = isS ? (ic * 11) >> 5 : (ic >> 3);  // /3 or /8, ic<=11
    const int tt = ic - gq * tpg;
    const int it = tt * 16 + mrow;
    int2 pr = make_int2(0, 0);
    if (it < P) {
      const int g2 = gbase + wave + 4 * gq;
      pr = ((const int2*)ids)[(size_t)g2 * P + it];
    }
    idreg = pr;
  };
  auto issue_gather = [&](float4* pfc, float& pm0, int& rid0)
      __attribute__((always_inline)) {
    const int iid = idreg.x;
    rid0 = idreg.y;
    pm0 = iid > 0 ? 1.f : 0.f;
    const float* ib = item_table + (size_t)iid * 64 + quad * 8;
    pfc[0] = ((const float4*)ib)[0];
    pfc[1] = ((const float4*)ib)[1];
    pfc[2] = ((const float4*)(ib + 32))[0];
    pfc[3] = ((const float4*)(ib + 32))[1];
  };
  load_ids(0); issue_gather(pfA, pmA, ridA);
  load_ids(1); issue_gather(pfB, pmB, ridB);
  load_ids(2);  // in flight across the prologue copies

  // ---- prologue: 8 coalesced float4 copies (img 28KB + sV 4KB/1KB) ----
  {
    const float4* src = (const float4*)img;
    float4* dst = (float4*)smem;
#pragma unroll
    for (int o = 0; o < 7; ++o) dst[tid + o * 256] = src[tid + o * 256];
    if (tid < NG * 16)
      ((float4*)sV)[tid] = ((const float4*)(sVws + (size_t)svbase * 64))[tid];
  }
  // per-lane constant preloads (global, L2-hot)
  float b2v[4], aw2v[4];
#pragma unroll
  for (int nt = 0; nt < 4; ++nt) {
    b2v[nt] = gv_b2[nt * 16 + mrow];
    aw2v[nt] = atti_W2[nt * 16 + mrow];
  }
  const float ab2 = atti_b2[0];
  __syncthreads();  // B3: images + sV ready

  // ---- hoist W1 A-frags + cstv from the copied image ----
  f16x8 aW[4][2];
#pragma unroll
  for (int nt = 0; nt < 4; ++nt) {
#pragma unroll
    for (int ks = 0; ks < 2; ++ks)
      aW[nt][ks] = *(const f16x8*)(smem + OFF_W1T + (nt * 16 + mrow) * 128 +
                                   (((ks * 4 + quad) ^ (mrow & 7)) << 4));
  }
  float cstv[4];
  {
    const float* cst = (const float*)(smem + OFF_CST);
#pragma unroll
    for (int nt = 0; nt < 4; ++nt) cstv[nt] = cst[nt * 16 + mrow];
  }
  __syncthreads();  // B4: hoist done; region A becomes per-wave H slots

  // =================== pipelined barrier-free main loop ===================
  const float* sR1 = (const float*)(smem + OFF_R1);
  float vv[4], pnum[4], pden = 0.f;
  auto tile_body = [&](float4* pfc, float& pmc, int& ridc, const int idx)
      __attribute__((always_inline)) {
    const int gq = isS ? (idx * 11) >> 5 : (idx >> 3);
    const int tt = idx - gq * tpg;
    const int g = wave + 4 * gq;
    if (tt == 0) {
#pragma unroll
      for (int nt = 0; nt < 4; ++nt) {
        vv[nt] = sV[g * 64 + nt * 16 + mrow];
        pnum[nt] = 0.f;
      }
      pden = 0.f;
    }
    // In B-frags straight from prefetched registers (no LDS)
    f16x8 bIn0 = cvt_f16x8(pfc[0], pfc[1]);
    f16x8 bIn1 = cvt_f16x8(pfc[2], pfc[3]);
    const unsigned long long mball = __ballot(pmc > 0.5f);
    const int ridcur = ridc;
    issue_gather(pfc, pmc, ridc);  // gather for tile idx+2 (ids in idreg)
    load_ids(idx + 3);             // ids for tile idx+3 -> idreg
    // ---- layer1 (transposed): H^T -> b64 writes to wave-private slot ----
#pragma unroll
    for (int nt = 0; nt < 4; ++nt) {
      f32x4 c = {0.f, 0.f, 0.f, 0.f};
      c = __builtin_amdgcn_mfma_f32_16x16x32_f16(aW[nt][0], bIn0, c, 0, 0, 0);
      c = __builtin_amdgcn_mfma_f32_16x16x32_f16(aW[nt][1], bIn1, c, 0, 0, 0);
      const float4 r1q = *(const float4*)(sR1 + ridcur * 68 + nt * 16 + quad * 4);
      const float* r1p = (const float*)&r1q;
      f16x4 hv;
#pragma unroll
      for (int rg = 0; rg < 4; ++rg)
        hv[rg] = (_Float16)fmaxf(c[rg] + r1p[rg], 0.f);
      *(f16x4*)(smXw + mrow * 128 +
                (((nt * 2 + (quad >> 1)) ^ (mrow & 7)) << 4) +
                ((quad & 1) << 3)) = hv;
    }
    // ---- H A-frags for layer2 + attention ----
    f16x8 a2[2];
#pragma unroll
    for (int ks = 0; ks < 2; ++ks)
      a2[ks] = *(const f16x8*)(smXw + mrow * 128 +
                               (((ks * 4 + quad) ^ (mrow & 7)) << 4));
    float mk[4];
#pragma unroll
    for (int rg = 0; rg < 4; ++rg)
      mk[rg] = (float)((mball >> (quad * 4 + rg)) & 1ULL);
    // d-path first (attention logits); c-path MFMAs are e-independent
    float tl[4] = {0.f, 0.f, 0.f, 0.f};
#pragma unroll
    for (int nt = 0; nt < 4; ++nt) {
      f32x4 d = {0.f, 0.f, 0.f, 0.f};
#pragma unroll
      for (int ks = 0; ks < 2; ++ks) {
        const f16x8 bM = *(const f16x8*)(smem + OFF_M2T + (nt * 16 + mrow) * 128 +
                                         (((ks * 4 + quad) ^ (mrow & 7)) << 4));
        d = __builtin_amdgcn_mfma_f32_16x16x32_f16(a2[ks], bM, d, 0, 0, 0);
      }
#pragma unroll
      for (int rg = 0; rg < 4; ++rg) {
        const float hh = fmaxf(d[rg] + cstv[nt] + mk[rg] * vv[nt], 0.f);
        tl[rg] = fmaf(hh, aw2v[nt], tl[rg]);
      }
    }
    float e[4];
#pragma unroll
    for (int rg = 0; rg < 4; ++rg) {
      float t = tl[rg];
      t = qpx1_add(t);          // xor-1 via DPP quad_perm (VALU)
      t = qpx2_add(t);          // xor-2 via DPP quad_perm (VALU)
      t += __shfl_xor(t, 4); t += __shfl_xor(t, 8);
      e[rg] = __expf(t + ab2) * mk[rg];
      pden += e[rg];
    }
    // c-path (x2) consumed straight into pnum (b2 folded at flush)
#pragma unroll
    for (int nt = 0; nt < 4; ++nt) {
      f32x4 c = {0.f, 0.f, 0.f, 0.f};
#pragma unroll
      for (int ks = 0; ks < 2; ++ks) {
        const f16x8 bW = *(const f16x8*)(smem + OFF_W2T + (nt * 16 + mrow) * 128 +
                                         (((ks * 4 + quad) ^ (mrow & 7)) << 4));
        c = __builtin_amdgcn_mfma_f32_16x16x32_f16(a2[ks], bW, c, 0, 0, 0);
      }
      pnum[nt] = fmaf(e[0], c[0], pnum[nt]);
      pnum[nt] = fmaf(e[1], c[1], pnum[nt]);
      pnum[nt] = fmaf(e[2], c[2], pnum[nt]);
      pnum[nt] = fmaf(e[3], c[3], pnum[nt]);
    }
    if (tt == tpg - 1) {
      // ---- group flush (wave-local): quad-reduce + agg matvec + store ----
      float dsum = pden;
      dsum += __shfl_xor(dsum, 16); dsum += __shfl_xor(dsum, 32);
      const float rd = 1.f / (dsum + EPSV);
#pragma unroll
      for (int nt = 0; nt < 4; ++nt) {
        float s = pnum[nt];
        s += __shfl_xor(s, 16); s += __shfl_xor(s, 32);
        if (quad == 0) csW[nt * 16 + mrow] = (s + b2v[nt] * dsum) * rd;
      }
      float acc = agg_b[lane];
#pragma unroll 8
      for (int k = 0; k < 64; ++k) acc = fmaf(csW[k], agg_W[k * 64 + lane], acc);
      out[(size_t)(gbase + g) * 64 + lane] = fmaxf(acc, 0.f);
    }
  };
  for (int idx = 0; idx < nIdx; idx += 2) {  // nIdx even (12 or 8)
    tile_body(pfA, pmA, ridA, idx);
    tile_body(pfB, pmB, ridB, idx + 1);
  }
}

// ---------------- stage2 LDS layout (bytes) ----------------
#define S2_W1T 0       // 17408: attu_W1^T f16 [n][k], pitch 272 (bank-rotated)
#define S2_X   17408   // 8704:  2 waves x 16 rows x 272B
#define S2_E   26112   // 128:   2 x 16 f32
#define S2_MSK 26240   // 128:   2 x 16 f32
#define S2_HB  26368   // 1536:  2 x 192 f32 (concat/hidden ping-pong)
#define S2_SZ  27904

// ---------------------------------------------------------------------------
// Kernel 2: beta attention (MFMA) + h_iS + final 3-layer MLP.
// 256 blocks x 128 thr; wave w handles b = blockIdx*2 + w autonomously.
// ---------------------------------------------------------------------------
__global__ __launch_bounds__(128, 2) void stage2_kernel(
    const int* __restrict__ u_user_pad, const float* __restrict__ user_table,
    const float* __restrict__ hoI, const float* __restrict__ hiI,
    const float* __restrict__ attu_W1, const float* __restrict__ attu_b1,
    const float* __restrict__ attu_W2, const float* __restrict__ attu_b2,
    const float* __restrict__ aggn_W, const float* __restrict__ aggn_b,
    const float* __restrict__ cm_W1, const float* __restrict__ cm_b1,
    const float* __restrict__ cm_W2, const float* __restrict__ cm_b2,
    const float* __restrict__ cm_W3, const float* __restrict__ cm_b3,
    float* __restrict__ out) {
  __shared__ __align__(16) char smem[S2_SZ];
  const int tid = threadIdx.x;
  const int wave = tid >> 6, lane = tid & 63;
  const int quad = lane >> 4, mrow = lane & 15;
  const int b = (int)blockIdx.x * 2 + wave;

  char* sW1 = smem + S2_W1T;
  char* sXw = smem + S2_X + wave * 4352;
  float* sE = (float*)(smem + S2_E) + wave * 16;
  float* sM = (float*)(smem + S2_MSK) + wave * 16;
  float* sB = (float*)(smem + S2_HB) + wave * 192;

  for (int o = tid; o < 2048; o += 128) {
    const int k = o >> 4, fb = o & 15;
    const float4 v = ((const float4*)(attu_W1 + k * 64))[fb];
    const float* vp = (const float*)&v;
#pragma unroll
    for (int c = 0; c < 4; ++c) {
      const int n = fb * 4 + c;
      *(_Float16*)(sW1 + n * 272 + ((k >> 3) << 4) + ((k & 7) << 1)) = (_Float16)vp[c];
    }
  }
  float b1v[4], w2v[4];
#pragma unroll
  for (int nt = 0; nt < 4; ++nt) {
    b1v[nt] = attu_b1[nt * 16 + mrow];
    w2v[nt] = attu_W2[nt * 16 + mrow];
  }
  const float b2s = attu_b2[0];

  float4 pa[4], pb[4];
  float msk[4];
  auto pf = [&](int tt) __attribute__((always_inline)) {
#pragma unroll
    for (int k = 0; k < 4; ++k) {
      const int u = lane + (k << 6);
      const int r = u >> 4, bb = u & 15;
      const int q = tt * 16 + r;
      const int qc = q < 40 ? q : 39;
      int uid = 0;
      float m = 0.f;
      if (q < 40) {
        uid = u_user_pad[b * 40 + q];
        m = uid > 0 ? 1.f : 0.f;
      }
      msk[k] = m;
      const float* src = (bb < 8)
                             ? hoI + ((size_t)b * 40 + qc) * 64 + bb * 8
                             : user_table + (size_t)uid * 64 + (bb - 8) * 8;
      pa[k] = ((const float4*)src)[0];
      pb[k] = ((const float4*)src)[1];
    }
  };
  pf(0);
  __syncthreads();  // W1T ready

  float numer = 0.f, pden = 0.f;
  for (int tt = 0; tt < 3; ++tt) {
#pragma unroll
    for (int k = 0; k < 4; ++k) {
      const int u = lane + (k << 6);
      const int r = u >> 4, bb = u & 15;
      *(f16x8*)(sXw + r * 272 + (bb << 4)) = cvt_f16x8(pa[k], pb[k]);
      if (bb == 0) sM[r] = msk[k];
    }
    if (tt < 2) pf(tt + 1);
    f16x8 a[4];
#pragma unroll
    for (int ks = 0; ks < 4; ++ks)
      a[ks] = *(const f16x8*)(sXw + mrow * 272 + ((ks * 4 + quad) << 4));
    float mk[4];
#pragma unroll
    for (int rg = 0; rg < 4; ++rg) mk[rg] = sM[quad * 4 + rg];
    float tl[4] = {0.f, 0.f, 0.f, 0.f};
#pragma unroll
    for (int nt = 0; nt < 4; ++nt) {
      f32x4 d = {0.f, 0.f, 0.f, 0.f};
      const int n = nt * 16 + mrow;
#pragma unroll
      for (int ks = 0; ks < 4; ++ks) {
        const f16x8 bW = *(const f16x8*)(sW1 + n * 272 + ((ks * 4 + quad) << 4));
        d = __builtin_amdgcn_mfma_f32_16x16x32_f16(a[ks], bW, d, 0, 0, 0);
      }
#pragma unroll
      for (int rg = 0; rg < 4; ++rg) {
        const float h = fmaxf(d[rg] + b1v[nt], 0.f);
        tl[rg] = fmaf(h, w2v[nt], tl[rg]);
      }
    }
    float e[4];
#pragma unroll
    for (int rg = 0; rg < 4; ++rg) {
      float t = tl[rg];
      t = qpx1_add(t);
      t = qpx2_add(t);
      t += __shfl_xor(t, 4); t += __shfl_xor(t, 8);
      e[rg] = __expf(t + b2s) * mk[rg];
      pden += e[rg];
    }
    if (mrow == 0) {
#pragma unroll
      for (int rg = 0; rg < 4; ++rg) sE[quad * 4 + rg] = e[rg];
    }
#pragma unroll 4
    for (int r = 0; r < 16; ++r) {
      const float er = sE[r];
      const float xv = (float)*(const _Float16*)(sXw + r * 272 + ((lane >> 3) << 4) +
                                                 ((lane & 7) << 1));
      numer = fmaf(er, xv, numer);
    }
  }
  pden += __shfl_xor(pden, 16);
  pden += __shfl_xor(pden, 32);
  const float hagg = numer / (pden + EPSV);

  sB[128 + lane] = hagg;
  sB[lane] = hiI[(size_t)b * 64 + lane];
  float acc = aggn_b[lane];
#pragma unroll 8
  for (int k = 0; k < 64; ++k) acc = fmaf(sB[128 + k], aggn_W[k * 64 + lane], acc);
  sB[64 + lane] = fmaxf(acc, 0.f);
  float c1 = cm_b1[lane];
#pragma unroll 8
  for (int k = 0; k < 128; ++k) c1 = fmaf(sB[k], cm_W1[k * 64 + lane], c1);
  sB[128 + lane] = fmaxf(c1, 0.f);
  float c2 = cm_b2[lane];
#pragma unroll 8
  for (int k = 0; k < 64; ++k) c2 = fmaf(sB[128 + k], cm_W2[k * 64 + lane], c2);
  sB[lane] = fmaxf(c2, 0.f);
  float c3 = cm_b3[lane];
#pragma unroll 8
  for (int k = 0; k < 64; ++k) c3 = fmaf(sB[k], cm_W3[k * 64 + lane], c3);
  out[(size_t)b * 64 + lane] = fmaxf(c3, 0.f);
}

extern "C" void kernel_launch(void* const* d_in, const int* in_sizes, int n_in,
                              void* d_out, int out_size, void* d_ws, size_t ws_size,
                              hipStream_t stream) {
  const int* uids = (const int*)d_in[0];
  const int* u_item_pad = (const int*)d_in[1];
  const int* u_user_pad = (const int*)d_in[2];
  const int* u_user_item_pad = (const int*)d_in[3];
  const float* user_table = (const float*)d_in[4];
  const float* item_table = (const float*)d_in[5];
  const float* rate_table = (const float*)d_in[6];
  const float* gv_W1 = (const float*)d_in[7];
  const float* gv_b1 = (const float*)d_in[8];
  const float* gv_W2 = (const float*)d_in[9];
  const float* gv_b2 = (const float*)d_in[10];
  const float* atti_W1 = (const float*)d_in[11];
  const float* atti_b1 = (const float*)d_in[12];
  const float* atti_W2 = (const float*)d_in[13];
  const float* atti_b2 = (const float*)d_in[14];
  const float* agg_W = (const float*)d_in[15];
  const float* agg_b = (const float*)d_in[16];
  const float* attu_W1 = (const float*)d_in[17];
  const float* attu_b1 = (const float*)d_in[18];
  const float* attu_W2 = (const float*)d_in[19];
  const float* attu_b2 = (const float*)d_in[20];
  const float* aggn_W = (const float*)d_in[21];
  const float* aggn_b = (const float*)d_in[22];
  const float* cm_W1 = (const float*)d_in[23];
  const float* cm_b1 = (const float*)d_in[24];
  const float* cm_W2 = (const float*)d_in[25];
  const float* cm_b2 = (const float*)d_in[26];
  const float* cm_W3 = (const float*)d_in[27];
  const float* cm_b3 = (const float*)d_in[28];
  float* out = (float*)d_out;

  float* hoI = (float*)d_ws;                    // 512*40*64 floats
  float* hiI = hoI + (size_t)512 * 40 * 64;     // 512*64 floats
  char* img = (char*)(hiI + (size_t)512 * 64);  // 28KB weight image
  float* sVws = (float*)(img + IMG_SZ);         // 20992*64 floats (~5.4MB)

  // One-time block-invariant work: image (5 blocks) + sV (1312 x 16 groups).
  prep_all<<<5 + 1312, 256, 0, stream>>>(rate_table, gv_W1, gv_b1, gv_W2,
                                         gv_b2, atti_W1, atti_b1,
                                         u_user_pad, uids, user_table,
                                         img, sVws);
  // Merged I (128 blocks x 4 groups, dispatched first) + S (1280 x 16).
  agg_kernel<<<128 + 1280, 256, 0, stream>>>(
      128, u_user_item_pad, u_item_pad, item_table,
      gv_b2, atti_W2, atti_b2, agg_W, agg_b, img, sVws, hoI, hiI);
  // Beta attention + h_iS + final MLP (wave-autonomous MFMA).
  stage2_kernel<<<256, 128, 0, stream>>>(u_user_pad, user_table, hoI, hiI,
                                         attu_W1, attu_b1, attu_W2, attu_b2,
                                         aggn_W, aggn_b,
                                         cm_W1, cm_b1, cm_W2, cm_b2, cm_W3, cm_b3,
                                         out);
}